// Round 1
// baseline (1600.702 us; speedup 1.0000x reference)
//
#include <hip/hip_runtime.h>
#include <math.h>

// Problem constants (shapes from reference): N=100000, E=1600000, C_IN=32, C_H=C_OUT=64, G=64
// All feature widths after layer 1 are 64 == wavefront size: one wave per node-row / per edge.

__device__ __forceinline__ int lower_bound_i(const int* __restrict__ a, int n, int v) {
    int lo = 0, hi = n;
    while (lo < hi) {
        int m = (lo + hi) >> 1;
        if (a[m] < v) lo = m + 1; else hi = m;
    }
    return lo;
}

__global__ void k_deg_init(float* deg, int n) {
    int i = blockIdx.x * blockDim.x + threadIdx.x;
    if (i < n) deg[i] = 1.0f;   // self-loop weight
}

__global__ void k_deg_edges(const int* __restrict__ dst, const float* __restrict__ ew,
                            float* deg, int e) {
    int i = blockIdx.x * blockDim.x + threadIdx.x;
    if (i < e) atomicAdd(&deg[dst[i]], ew[i]);
}

__global__ void k_dis(float* deg_dis, int n) {
    int i = blockIdx.x * blockDim.x + threadIdx.x;
    if (i < n) {
        float d = deg_dis[i];
        deg_dis[i] = d > 0.0f ? rsqrtf(d) : 0.0f;
    }
}

__global__ void k_norm(const int* __restrict__ src, const int* __restrict__ dst,
                       const float* __restrict__ ew, const float* __restrict__ dis,
                       float* __restrict__ norm, int e) {
    int i = blockIdx.x * blockDim.x + threadIdx.x;
    if (i < e) norm[i] = dis[src[i]] * ew[i] * dis[dst[i]];
}

// h2[row, col] = sum_k h[row,k] * W[k,col];  col width fixed at 64, K templated (32 or 64).
template <int K>
__global__ void k_matmul(const float* __restrict__ h, const float* __restrict__ W,
                         float* __restrict__ out, int n) {
    __shared__ float sW[K * 64];
    for (int t = threadIdx.x; t < K * 64; t += blockDim.x) sW[t] = W[t];
    __syncthreads();
    int idx = blockIdx.x * blockDim.x + threadIdx.x;
    int row = idx >> 6, col = idx & 63;
    if (row >= n) return;
    const float* hr = h + (size_t)row * K;
    float acc = 0.0f;
#pragma unroll
    for (int k = 0; k < K; ++k) acc = fmaf(hr[k], sW[k * 64 + col], acc);
    out[idx] = acc;
}

// agg init with self-loop contribution: agg[i,c] = h2[i,c] * dis[i]^2
__global__ void k_selfinit(const float* __restrict__ h2, const float* __restrict__ dis,
                           float* __restrict__ agg, int n) {
    int idx = blockIdx.x * blockDim.x + threadIdx.x;
    int row = idx >> 6;
    if (row < n) {
        float s = dis[row];
        agg[idx] = h2[idx] * (s * s);
    }
}

// one wave per edge; lane = channel. Coalesced 256B gather + 64-lane atomic scatter.
__global__ void k_edge_agg(const int* __restrict__ src, const int* __restrict__ dst,
                           const float* __restrict__ norm, const float* __restrict__ h2,
                           float* __restrict__ agg, int e) {
    int idx = blockIdx.x * blockDim.x + threadIdx.x;
    int eid = idx >> 6, lane = idx & 63;
    if (eid >= e) return;
    int s = src[eid];
    int d = dst[eid];
    float w = norm[eid];
    float v = h2[(size_t)s * 64 + lane] * w;
    atomicAdd(&agg[(size_t)d * 64 + lane], v);
}

__global__ void k_bias_silu(float* __restrict__ h, const float* __restrict__ b, int total) {
    int idx = blockIdx.x * blockDim.x + threadIdx.x;
    if (idx < total) {
        float v = h[idx] + b[idx & 63];
        h[idx] = v / (1.0f + __expf(-v));
    }
}

// batch is sorted: graph g owns contiguous rows [lb(g), lb(g+1)). One block per graph.
__global__ void k_pool(const float* __restrict__ h, const int* __restrict__ batch,
                       float* __restrict__ out, int n) {
    int g = blockIdx.x;
    int c = threadIdx.x & 63, r = threadIdx.x >> 6;   // 256 threads = 4 row-groups x 64 ch
    int lo = lower_bound_i(batch, n, g);
    int hi = lower_bound_i(batch, n, g + 1);
    float acc = 0.0f;
    for (int i = lo + r; i < hi; i += 4) acc += h[(size_t)i * 64 + c];
    __shared__ float part[4][64];
    part[r][c] = acc;
    __syncthreads();
    if (r == 0) {
        float s = part[0][c] + part[1][c] + part[2][c] + part[3][c];
        int cnt = hi - lo;
        out[g * 64 + c] = s / (float)(cnt > 0 ? cnt : 1);
    }
}

extern "C" void kernel_launch(void* const* d_in, const int* in_sizes, int n_in,
                              void* d_out, int out_size, void* d_ws, size_t ws_size,
                              hipStream_t stream) {
    const float* x   = (const float*)d_in[0];
    const float* ew  = (const float*)d_in[1];
    const float* W1  = (const float*)d_in[2];
    const float* b1  = (const float*)d_in[3];
    const float* W2  = (const float*)d_in[4];
    const float* b2  = (const float*)d_in[5];
    const float* W3  = (const float*)d_in[6];
    const float* b3  = (const float*)d_in[7];
    const int*   eidx  = (const int*)d_in[8];
    const int*   batch = (const int*)d_in[9];
    float* out = (float*)d_out;

    const int E = in_sizes[1];       // 1,600,000
    const int N = in_sizes[9];       // 100,000
    const int* src = eidx;           // edge_index[0]
    const int* dst = eidx + E;       // edge_index[1]

    float* A   = (float*)d_ws;              // N*64
    float* B   = A + (size_t)N * 64;        // N*64
    float* dis = B + (size_t)N * 64;        // N  (holds deg, then dis in-place)
    float* nrm = dis + N;                   // E

    const int BT = 256;
    int gN  = (N + BT - 1) / BT;
    int gEt = (E + BT - 1) / BT;
    int gNC = (N * 64 + BT - 1) / BT;                         // node x channel grid
    int gEC = (int)(((long long)E * 64 + BT - 1) / BT);        // edge x channel grid
    int totNC = N * 64;

    // --- normalization (shared across layers) ---
    k_deg_init<<<gN, BT, 0, stream>>>(dis, N);
    k_deg_edges<<<gEt, BT, 0, stream>>>(dst, ew, dis, E);
    k_dis<<<gN, BT, 0, stream>>>(dis, N);
    k_norm<<<gEt, BT, 0, stream>>>(src, dst, ew, dis, nrm, E);

    // --- layer 1: h=x (K=32) -> h2=B; agg=A; silu in place ---
    k_matmul<32><<<gNC, BT, 0, stream>>>(x, W1, B, N);
    k_selfinit<<<gNC, BT, 0, stream>>>(B, dis, A, N);
    k_edge_agg<<<gEC, BT, 0, stream>>>(src, dst, nrm, B, A, E);
    k_bias_silu<<<gNC, BT, 0, stream>>>(A, b1, totNC);

    // --- layer 2: h=A -> h2=B; A dead after matmul -> agg=A ---
    k_matmul<64><<<gNC, BT, 0, stream>>>(A, W2, B, N);
    k_selfinit<<<gNC, BT, 0, stream>>>(B, dis, A, N);
    k_edge_agg<<<gEC, BT, 0, stream>>>(src, dst, nrm, B, A, E);
    k_bias_silu<<<gNC, BT, 0, stream>>>(A, b2, totNC);

    // --- layer 3 ---
    k_matmul<64><<<gNC, BT, 0, stream>>>(A, W3, B, N);
    k_selfinit<<<gNC, BT, 0, stream>>>(B, dis, A, N);
    k_edge_agg<<<gEC, BT, 0, stream>>>(src, dst, nrm, B, A, E);
    k_bias_silu<<<gNC, BT, 0, stream>>>(A, b3, totNC);

    // --- mean pool (batch sorted -> contiguous ranges, no atomics) ---
    k_pool<<<64, BT, 0, stream>>>(A, batch, out, N);
}

// Round 2
// 837.380 us; speedup vs baseline: 1.9116x; 1.9116x over previous
//
#include <hip/hip_runtime.h>
#include <math.h>

// GCN encoder, N=100000, E=1600000, C_IN=32, C_H=C_OUT=64, G=64.
// Strategy: build CSR (edges sorted by dst) once, pull-based aggregation
// (no float atomics), aggregate BEFORE matmul (linearity), matmul with
// register-resident W + fused bias/SiLU.

struct __align__(8) EdgeM { int s; float w; };

__device__ __forceinline__ int lower_bound_i(const int* __restrict__ a, int n, int v) {
    int lo = 0, hi = n;
    while (lo < hi) {
        int m = (lo + hi) >> 1;
        if (a[m] < v) lo = m + 1; else hi = m;
    }
    return lo;
}

// rowptr(cnt)=0, deg=1 (self-loop weight)
__global__ void k_init(int* cnt, float* deg, int n) {
    int i = blockIdx.x * blockDim.x + threadIdx.x;
    if (i < n) { cnt[i] = 0; deg[i] = 1.0f; }
}

__global__ void k_hist(const int* __restrict__ dst, const float* __restrict__ ew,
                       int* cnt, float* deg, int e) {
    int i = blockIdx.x * blockDim.x + threadIdx.x;
    if (i < e) {
        int d = dst[i];
        atomicAdd(&cnt[d], 1);
        atomicAdd(&deg[d], ew[i]);
    }
}

__global__ void k_dis(float* deg_dis, int n) {
    int i = blockIdx.x * blockDim.x + threadIdx.x;
    if (i < n) deg_dis[i] = rsqrtf(deg_dis[i]);   // deg >= 1 always (self-loop)
}

// exclusive scan of cnt (in place -> rowptr partial), per-block, bsums[b]=block total
__global__ void k_scan1(int* data, int* bsums, int n) {
    __shared__ int s[256];
    int tid = threadIdx.x;
    int i = blockIdx.x * 256 + tid;
    int v = (i < n) ? data[i] : 0;
    s[tid] = v;
    __syncthreads();
    for (int off = 1; off < 256; off <<= 1) {
        int t = (tid >= off) ? s[tid - off] : 0;
        __syncthreads();
        s[tid] += t;
        __syncthreads();
    }
    if (i < n) data[i] = s[tid] - v;           // exclusive within block
    if (tid == 255) bsums[blockIdx.x] = s[255];
}

__global__ void k_scan2(int* bsums, int nb) {   // single block, 512 threads
    __shared__ int s[512];
    int tid = threadIdx.x;
    int v = (tid < nb) ? bsums[tid] : 0;
    s[tid] = v;
    __syncthreads();
    for (int off = 1; off < 512; off <<= 1) {
        int t = (tid >= off) ? s[tid - off] : 0;
        __syncthreads();
        s[tid] += t;
        __syncthreads();
    }
    if (tid < nb) bsums[tid] = s[tid] - v;      // exclusive
}

__global__ void k_scan3(int* rowptr, const int* __restrict__ bsums, int* cursor, int n, int e) {
    int i = blockIdx.x * blockDim.x + threadIdx.x;
    if (i < n) {
        int v = rowptr[i] + bsums[i >> 8];
        rowptr[i] = v;
        cursor[i] = v;
        if (i == 0) rowptr[n] = e;
    }
}

__global__ void k_scatter(const int* __restrict__ src, const int* __restrict__ dst,
                          const float* __restrict__ ew, const float* __restrict__ dis,
                          int* cursor, int2* __restrict__ em, int e) {
    int i = blockIdx.x * blockDim.x + threadIdx.x;
    if (i < e) {
        int s = src[i], d = dst[i];
        float w = dis[s] * ew[i] * dis[d];
        int pos = atomicAdd(&cursor[d], 1);
        em[pos] = make_int2(s, __float_as_int(w));
    }
}

// pull aggregation, 64 channels: one wave per node, lane = channel.
__global__ void k_agg64(const float* __restrict__ h, const int2* __restrict__ em,
                        const int* __restrict__ rowptr, const float* __restrict__ dis,
                        float* __restrict__ out, int n) {
    int gid = blockIdx.x * blockDim.x + threadIdx.x;
    int node = gid >> 6, lane = gid & 63;
    if (node >= n) return;
    int lo = rowptr[node], hi = rowptr[node + 1];
    float di = dis[node];
    float acc = di * di * h[(size_t)node * 64 + lane];   // self-loop
    int j = lo;
    for (; j + 1 < hi; j += 2) {
        int2 e0 = em[j], e1 = em[j + 1];
        float v0 = h[(size_t)e0.x * 64 + lane];
        float v1 = h[(size_t)e1.x * 64 + lane];
        acc = fmaf(__int_as_float(e0.y), v0, acc);
        acc = fmaf(__int_as_float(e1.y), v1, acc);
    }
    if (j < hi) {
        int2 e0 = em[j];
        acc = fmaf(__int_as_float(e0.y), h[(size_t)e0.x * 64 + lane], acc);
    }
    out[(size_t)node * 64 + lane] = acc;
}

// pull aggregation, 32 channels (layer-1 input x): half-wave per edge-stream.
__global__ void k_agg32(const float* __restrict__ h, const int2* __restrict__ em,
                        const int* __restrict__ rowptr, const float* __restrict__ dis,
                        float* __restrict__ out, int n) {
    int gid = blockIdx.x * blockDim.x + threadIdx.x;
    int node = gid >> 6, lane = gid & 63;
    if (node >= n) return;
    int c = lane & 31, half = lane >> 5;
    int lo = rowptr[node], hi = rowptr[node + 1];
    float di = dis[node];
    float acc = (half == 0) ? di * di * h[(size_t)node * 32 + c] : 0.0f;
    for (int j = lo + half; j < hi; j += 2) {
        int2 ev = em[j];
        acc = fmaf(__int_as_float(ev.y), h[(size_t)ev.x * 32 + c], acc);
    }
    acc += __shfl_down(acc, 32, 64);
    if (half == 0) out[(size_t)node * 32 + c] = acc;
}

// out[row,col] = silu( sum_k agg[row,k]*W[k,col] + b[col] ); W column in regs.
template <int K>
__global__ __launch_bounds__(256) void k_mm(const float* __restrict__ agg,
                                            const float* __restrict__ W,
                                            const float* __restrict__ b,
                                            float* __restrict__ out, int n) {
    int lane = threadIdx.x & 63;
    float w[K];
#pragma unroll
    for (int k = 0; k < K; ++k) w[k] = W[k * 64 + lane];
    float bias = b[lane];
    int wid = (blockIdx.x * blockDim.x + threadIdx.x) >> 6;
    int nw = (gridDim.x * blockDim.x) >> 6;
    for (int row = wid; row < n; row += nw) {
        const float* ar = agg + (size_t)row * K;
        float o = bias;
#pragma unroll
        for (int k = 0; k < K; k += 4) {
            float4 a4 = *(const float4*)(ar + k);
            o = fmaf(a4.x, w[k + 0], o);
            o = fmaf(a4.y, w[k + 1], o);
            o = fmaf(a4.z, w[k + 2], o);
            o = fmaf(a4.w, w[k + 3], o);
        }
        o = o / (1.0f + __expf(-o));
        out[(size_t)row * 64 + lane] = o;
    }
}

// batch sorted -> contiguous ranges per graph; one block per graph.
__global__ void k_pool(const float* __restrict__ h, const int* __restrict__ batch,
                       float* __restrict__ out, int n) {
    int g = blockIdx.x;
    int c = threadIdx.x & 63, r = threadIdx.x >> 6;
    int lo = lower_bound_i(batch, n, g);
    int hi = lower_bound_i(batch, n, g + 1);
    float acc = 0.0f;
    for (int i = lo + r; i < hi; i += 4) acc += h[(size_t)i * 64 + c];
    __shared__ float part[4][64];
    part[r][c] = acc;
    __syncthreads();
    if (r == 0) {
        float s = part[0][c] + part[1][c] + part[2][c] + part[3][c];
        int cnt = hi - lo;
        out[g * 64 + c] = s / (float)(cnt > 0 ? cnt : 1);
    }
}

extern "C" void kernel_launch(void* const* d_in, const int* in_sizes, int n_in,
                              void* d_out, int out_size, void* d_ws, size_t ws_size,
                              hipStream_t stream) {
    const float* x   = (const float*)d_in[0];
    const float* ew  = (const float*)d_in[1];
    const float* W1  = (const float*)d_in[2];
    const float* b1  = (const float*)d_in[3];
    const float* W2  = (const float*)d_in[4];
    const float* b2  = (const float*)d_in[5];
    const float* W3  = (const float*)d_in[6];
    const float* b3  = (const float*)d_in[7];
    const int*   eidx  = (const int*)d_in[8];
    const int*   batch = (const int*)d_in[9];
    float* out = (float*)d_out;

    const int E = in_sizes[1];       // 1,600,000
    const int N = in_sizes[9];       // 100,000
    const int* src = eidx;
    const int* dst = eidx + E;

    // workspace layout
    char* p = (char*)d_ws;
    float* A      = (float*)p;                 p += (size_t)N * 64 * sizeof(float);
    float* B      = (float*)p;                 p += (size_t)N * 64 * sizeof(float);
    float* dis    = (float*)p;                 p += (size_t)N * sizeof(float);
    int*   rowptr = (int*)p;                   p += (size_t)(N + 1) * sizeof(int);
    int*   cursor = (int*)p;                   p += (size_t)N * sizeof(int);
    int*   bsums  = (int*)p;                   p += 1024 * sizeof(int);
    p = (char*)(((uintptr_t)p + 7) & ~(uintptr_t)7);
    int2*  em     = (int2*)p;                  // E entries, 8B each

    const int BT = 256;
    int gN  = (N + BT - 1) / BT;
    int gE  = (E + BT - 1) / BT;
    int gNC = (N * 64 + BT - 1) / BT;
    int nb  = gN;                              // blocks in scan1 (391 <= 512)

    // --- CSR build + normalization (shared across layers) ---
    k_init<<<gN, BT, 0, stream>>>(rowptr, dis, N);
    k_hist<<<gE, BT, 0, stream>>>(dst, ew, rowptr, dis, E);
    k_dis<<<gN, BT, 0, stream>>>(dis, N);
    k_scan1<<<nb, 256, 0, stream>>>(rowptr, bsums, N);
    k_scan2<<<1, 512, 0, stream>>>(bsums, nb);
    k_scan3<<<gN, BT, 0, stream>>>(rowptr, bsums, cursor, N, E);
    k_scatter<<<gE, BT, 0, stream>>>(src, dst, ew, dis, cursor, em, E);

    // --- layer 1: agg(x) [N,32] -> A ; A@W1+b1, silu -> B ---
    k_agg32<<<gNC, BT, 0, stream>>>(x, em, rowptr, dis, A, N);
    k_mm<32><<<960, BT, 0, stream>>>(A, W1, b1, B, N);

    // --- layer 2: agg(B) -> A ; A@W2+b2, silu -> B ---
    k_agg64<<<gNC, BT, 0, stream>>>(B, em, rowptr, dis, A, N);
    k_mm<64><<<960, BT, 0, stream>>>(A, W2, b2, B, N);

    // --- layer 3 ---
    k_agg64<<<gNC, BT, 0, stream>>>(B, em, rowptr, dis, A, N);
    k_mm<64><<<960, BT, 0, stream>>>(A, W3, b3, B, N);

    // --- mean pool ---
    k_pool<<<64, BT, 0, stream>>>(B, batch, out, N);
}

// Round 3
// 648.984 us; speedup vs baseline: 2.4665x; 1.2903x over previous
//
#include <hip/hip_runtime.h>
#include <math.h>

// GCN encoder, N=100000, E=1600000, C_IN=32, C_H=C_OUT=64, G=64.
// CSR build with ONE packed 64-bit atomic per edge (cnt in high 24 bits,
// fixed-point 20.20 sum(ew) in low 40); atomic's return value gives each
// edge its rank -> scatter is deterministic (atomic-free). Pull-based
// aggregation (no float atomics), aggregate BEFORE matmul (linearity),
// matmul with register-resident W + fused bias/SiLU.

#define FIXP_SCALE 1048576.0f   // 2^20
#define FIXP_MASK  ((1ULL << 40) - 1)

__device__ __forceinline__ int lower_bound_i(const int* __restrict__ a, int n, int v) {
    int lo = 0, hi = n;
    while (lo < hi) {
        int m = (lo + hi) >> 1;
        if (a[m] < v) lo = m + 1; else hi = m;
    }
    return lo;
}

__global__ void k_zero64(unsigned long long* cnt64, int n) {
    int i = blockIdx.x * blockDim.x + threadIdx.x;
    if (i < n) cnt64[i] = 0ULL;
}

// one packed atomic per edge; return value's high bits = this edge's rank in bucket
__global__ void k_hist(const int* __restrict__ dst, const float* __restrict__ ew,
                       unsigned long long* cnt64, int* __restrict__ rank, int e) {
    int i = blockIdx.x * blockDim.x + threadIdx.x;
    if (i < e) {
        int d = dst[i];
        unsigned long long pack =
            (1ULL << 40) | (unsigned long long)(ew[i] * FIXP_SCALE);
        unsigned long long old = atomicAdd(&cnt64[d], pack);
        rank[i] = (int)(old >> 40);
    }
}

// cnt64 -> cnt (for scan) + dis = rsqrt(1 + sum_ew)
__global__ void k_unpack(const unsigned long long* __restrict__ cnt64,
                         int* __restrict__ cnt, float* __restrict__ dis, int n) {
    int i = blockIdx.x * blockDim.x + threadIdx.x;
    if (i < n) {
        unsigned long long v = cnt64[i];
        cnt[i] = (int)(v >> 40);
        dis[i] = rsqrtf(1.0f + (float)(v & FIXP_MASK) * (1.0f / FIXP_SCALE));
    }
}

// exclusive scan of cnt (in place), per-block partials
__global__ void k_scan1(int* data, int* bsums, int n) {
    __shared__ int s[256];
    int tid = threadIdx.x;
    int i = blockIdx.x * 256 + tid;
    int v = (i < n) ? data[i] : 0;
    s[tid] = v;
    __syncthreads();
    for (int off = 1; off < 256; off <<= 1) {
        int t = (tid >= off) ? s[tid - off] : 0;
        __syncthreads();
        s[tid] += t;
        __syncthreads();
    }
    if (i < n) data[i] = s[tid] - v;
    if (tid == 255) bsums[blockIdx.x] = s[255];
}

__global__ void k_scan2(int* bsums, int nb) {   // single block, 512 threads
    __shared__ int s[512];
    int tid = threadIdx.x;
    int v = (tid < nb) ? bsums[tid] : 0;
    s[tid] = v;
    __syncthreads();
    for (int off = 1; off < 512; off <<= 1) {
        int t = (tid >= off) ? s[tid - off] : 0;
        __syncthreads();
        s[tid] += t;
        __syncthreads();
    }
    if (tid < nb) bsums[tid] = s[tid] - v;
}

__global__ void k_scan3(int* rowptr, const int* __restrict__ bsums, int n, int e) {
    int i = blockIdx.x * blockDim.x + threadIdx.x;
    if (i < n) {
        rowptr[i] += bsums[i >> 8];
        if (i == 0) rowptr[n] = e;
    }
}

// deterministic scatter: pos = rowptr[d] + rank[i]; no atomics.
__global__ void k_scatter(const int* __restrict__ src, const int* __restrict__ dst,
                          const float* __restrict__ ew, const float* __restrict__ dis,
                          const int* __restrict__ rowptr, const int* __restrict__ rank,
                          int2* __restrict__ em, int e) {
    int i = blockIdx.x * blockDim.x + threadIdx.x;
    if (i < e) {
        int s = src[i], d = dst[i];
        float w = dis[s] * ew[i] * dis[d];
        int pos = rowptr[d] + rank[i];
        em[pos] = make_int2(s, __float_as_int(w));
    }
}

// pull aggregation, 64 channels: one wave per node, lane = channel. unroll 4.
__global__ void k_agg64(const float* __restrict__ h, const int2* __restrict__ em,
                        const int* __restrict__ rowptr, const float* __restrict__ dis,
                        float* __restrict__ out, int n) {
    int gid = blockIdx.x * blockDim.x + threadIdx.x;
    int node = gid >> 6, lane = gid & 63;
    if (node >= n) return;
    int lo = rowptr[node], hi = rowptr[node + 1];
    float di = dis[node];
    float acc = di * di * h[(size_t)node * 64 + lane];   // self-loop
    int j = lo;
    for (; j + 3 < hi; j += 4) {
        int2 e0 = em[j], e1 = em[j + 1], e2 = em[j + 2], e3 = em[j + 3];
        float v0 = h[(size_t)e0.x * 64 + lane];
        float v1 = h[(size_t)e1.x * 64 + lane];
        float v2 = h[(size_t)e2.x * 64 + lane];
        float v3 = h[(size_t)e3.x * 64 + lane];
        acc = fmaf(__int_as_float(e0.y), v0, acc);
        acc = fmaf(__int_as_float(e1.y), v1, acc);
        acc = fmaf(__int_as_float(e2.y), v2, acc);
        acc = fmaf(__int_as_float(e3.y), v3, acc);
    }
    for (; j < hi; ++j) {
        int2 e0 = em[j];
        acc = fmaf(__int_as_float(e0.y), h[(size_t)e0.x * 64 + lane], acc);
    }
    out[(size_t)node * 64 + lane] = acc;
}

// pull aggregation, 32 channels (layer-1 input x): two edges in flight per wave.
__global__ void k_agg32(const float* __restrict__ h, const int2* __restrict__ em,
                        const int* __restrict__ rowptr, const float* __restrict__ dis,
                        float* __restrict__ out, int n) {
    int gid = blockIdx.x * blockDim.x + threadIdx.x;
    int node = gid >> 6, lane = gid & 63;
    if (node >= n) return;
    int c = lane & 31, half = lane >> 5;
    int lo = rowptr[node], hi = rowptr[node + 1];
    float di = dis[node];
    float acc = (half == 0) ? di * di * h[(size_t)node * 32 + c] : 0.0f;
    int j = lo + half;
    for (; j + 2 < hi; j += 4) {
        int2 ea = em[j], eb = em[j + 2];
        float va = h[(size_t)ea.x * 32 + c];
        float vb = h[(size_t)eb.x * 32 + c];
        acc = fmaf(__int_as_float(ea.y), va, acc);
        acc = fmaf(__int_as_float(eb.y), vb, acc);
    }
    if (j < hi) {
        int2 ev = em[j];
        acc = fmaf(__int_as_float(ev.y), h[(size_t)ev.x * 32 + c], acc);
    }
    acc += __shfl_down(acc, 32, 64);
    if (half == 0) out[(size_t)node * 32 + c] = acc;
}

// out[row,col] = silu( sum_k agg[row,k]*W[k,col] + b[col] ); W column in regs.
template <int K>
__global__ __launch_bounds__(256) void k_mm(const float* __restrict__ agg,
                                            const float* __restrict__ W,
                                            const float* __restrict__ b,
                                            float* __restrict__ out, int n) {
    int lane = threadIdx.x & 63;
    float w[K];
#pragma unroll
    for (int k = 0; k < K; ++k) w[k] = W[k * 64 + lane];
    float bias = b[lane];
    int wid = (blockIdx.x * blockDim.x + threadIdx.x) >> 6;
    int nw = (gridDim.x * blockDim.x) >> 6;
    for (int row = wid; row < n; row += nw) {
        const float* ar = agg + (size_t)row * K;
        float o = bias;
#pragma unroll
        for (int k = 0; k < K; k += 4) {
            float4 a4 = *(const float4*)(ar + k);
            o = fmaf(a4.x, w[k + 0], o);
            o = fmaf(a4.y, w[k + 1], o);
            o = fmaf(a4.z, w[k + 2], o);
            o = fmaf(a4.w, w[k + 3], o);
        }
        o = o / (1.0f + __expf(-o));
        out[(size_t)row * 64 + lane] = o;
    }
}

// batch sorted -> contiguous ranges per graph; one block per graph.
__global__ void k_pool(const float* __restrict__ h, const int* __restrict__ batch,
                       float* __restrict__ out, int n) {
    int g = blockIdx.x;
    int c = threadIdx.x & 63, r = threadIdx.x >> 6;
    int lo = lower_bound_i(batch, n, g);
    int hi = lower_bound_i(batch, n, g + 1);
    float acc = 0.0f;
    for (int i = lo + r; i < hi; i += 4) acc += h[(size_t)i * 64 + c];
    __shared__ float part[4][64];
    part[r][c] = acc;
    __syncthreads();
    if (r == 0) {
        float s = part[0][c] + part[1][c] + part[2][c] + part[3][c];
        int cnt = hi - lo;
        out[g * 64 + c] = s / (float)(cnt > 0 ? cnt : 1);
    }
}

extern "C" void kernel_launch(void* const* d_in, const int* in_sizes, int n_in,
                              void* d_out, int out_size, void* d_ws, size_t ws_size,
                              hipStream_t stream) {
    const float* x   = (const float*)d_in[0];
    const float* ew  = (const float*)d_in[1];
    const float* W1  = (const float*)d_in[2];
    const float* b1  = (const float*)d_in[3];
    const float* W2  = (const float*)d_in[4];
    const float* b2  = (const float*)d_in[5];
    const float* W3  = (const float*)d_in[6];
    const float* b3  = (const float*)d_in[7];
    const int*   eidx  = (const int*)d_in[8];
    const int*   batch = (const int*)d_in[9];
    float* out = (float*)d_out;

    const int E = in_sizes[1];       // 1,600,000
    const int N = in_sizes[9];       // 100,000
    const int* src = eidx;
    const int* dst = eidx + E;

    // workspace layout: A and B double as CSR-build scratch (cnt64 in A,
    // rank in B) since both are first written only after k_scatter.
    char* p = (char*)d_ws;
    float* A      = (float*)p;                 p += (size_t)N * 64 * sizeof(float);
    float* B      = (float*)p;                 p += (size_t)N * 64 * sizeof(float);
    float* dis    = (float*)p;                 p += (size_t)N * sizeof(float);
    int*   rowptr = (int*)p;                   p += (size_t)(N + 1) * sizeof(int);
    int*   bsums  = (int*)p;                   p += 1024 * sizeof(int);
    p = (char*)(((uintptr_t)p + 7) & ~(uintptr_t)7);
    int2*  em     = (int2*)p;                  // E entries, 8B each

    unsigned long long* cnt64 = (unsigned long long*)A;   // N * 8B < N*64*4B
    int* rank = (int*)B;                                  // E * 4B  < N*64*4B

    const int BT = 256;
    int gN  = (N + BT - 1) / BT;
    int gE  = (E + BT - 1) / BT;
    int gNC = (N * 64 + BT - 1) / BT;
    int nb  = gN;                              // blocks in scan1 (391 <= 512)

    // --- CSR build + normalization (shared across layers) ---
    k_zero64<<<gN, BT, 0, stream>>>(cnt64, N);
    k_hist<<<gE, BT, 0, stream>>>(dst, ew, cnt64, rank, E);
    k_unpack<<<gN, BT, 0, stream>>>(cnt64, rowptr, dis, N);
    k_scan1<<<nb, 256, 0, stream>>>(rowptr, bsums, N);
    k_scan2<<<1, 512, 0, stream>>>(bsums, nb);
    k_scan3<<<gN, BT, 0, stream>>>(rowptr, bsums, N, E);
    k_scatter<<<gE, BT, 0, stream>>>(src, dst, ew, dis, rowptr, rank, em, E);

    // --- layer 1: agg(x) [N,32] -> A ; A@W1+b1, silu -> B ---
    k_agg32<<<gNC, BT, 0, stream>>>(x, em, rowptr, dis, A, N);
    k_mm<32><<<960, BT, 0, stream>>>(A, W1, b1, B, N);

    // --- layer 2: agg(B) -> A ; A@W2+b2, silu -> B ---
    k_agg64<<<gNC, BT, 0, stream>>>(B, em, rowptr, dis, A, N);
    k_mm<64><<<960, BT, 0, stream>>>(A, W2, b2, B, N);

    // --- layer 3 ---
    k_agg64<<<gNC, BT, 0, stream>>>(B, em, rowptr, dis, A, N);
    k_mm<64><<<960, BT, 0, stream>>>(A, W3, b3, B, N);

    // --- mean pool ---
    k_pool<<<64, BT, 0, stream>>>(B, batch, out, N);
}

// Round 4
// 577.079 us; speedup vs baseline: 2.7738x; 1.1246x over previous
//
#include <hip/hip_runtime.h>
#include <math.h>

// GCN encoder, N=100000, E=1600000, C_IN=32, C_H=C_OUT=64, G=64.
// CSR build with ONE packed 64-bit atomic per edge (cnt in high 24 bits,
// fixed-point 20.20 sum(ew) in low 40); atomic's return value gives each
// edge its rank -> scatter is deterministic (atomic-free). Pull-based
// aggregation (no float atomics), aggregate BEFORE matmul (linearity),
// matmul with register-resident W + fused bias/SiLU. Pool: two-phase
// (per-chunk partial + segment-flush atomics, then finalize/divide).

#define FIXP_SCALE 1048576.0f   // 2^20
#define FIXP_MASK  ((1ULL << 40) - 1)

__device__ __forceinline__ int lower_bound_i(const int* __restrict__ a, int n, int v) {
    int lo = 0, hi = n;
    while (lo < hi) {
        int m = (lo + hi) >> 1;
        if (a[m] < v) lo = m + 1; else hi = m;
    }
    return lo;
}

__global__ void k_zero64(unsigned long long* cnt64, int n) {
    int i = blockIdx.x * blockDim.x + threadIdx.x;
    if (i < n) cnt64[i] = 0ULL;
}

// one packed atomic per edge; return value's high bits = this edge's rank in bucket
__global__ void k_hist(const int* __restrict__ dst, const float* __restrict__ ew,
                       unsigned long long* cnt64, int* __restrict__ rank, int e) {
    int i = blockIdx.x * blockDim.x + threadIdx.x;
    if (i < e) {
        int d = dst[i];
        unsigned long long pack =
            (1ULL << 40) | (unsigned long long)(ew[i] * FIXP_SCALE);
        unsigned long long old = atomicAdd(&cnt64[d], pack);
        rank[i] = (int)(old >> 40);
    }
}

// cnt64 -> cnt (for scan) + dis = rsqrt(1 + sum_ew)
__global__ void k_unpack(const unsigned long long* __restrict__ cnt64,
                         int* __restrict__ cnt, float* __restrict__ dis, int n) {
    int i = blockIdx.x * blockDim.x + threadIdx.x;
    if (i < n) {
        unsigned long long v = cnt64[i];
        cnt[i] = (int)(v >> 40);
        dis[i] = rsqrtf(1.0f + (float)(v & FIXP_MASK) * (1.0f / FIXP_SCALE));
    }
}

// exclusive scan of cnt (in place), per-block partials
__global__ void k_scan1(int* data, int* bsums, int n) {
    __shared__ int s[256];
    int tid = threadIdx.x;
    int i = blockIdx.x * 256 + tid;
    int v = (i < n) ? data[i] : 0;
    s[tid] = v;
    __syncthreads();
    for (int off = 1; off < 256; off <<= 1) {
        int t = (tid >= off) ? s[tid - off] : 0;
        __syncthreads();
        s[tid] += t;
        __syncthreads();
    }
    if (i < n) data[i] = s[tid] - v;
    if (tid == 255) bsums[blockIdx.x] = s[255];
}

__global__ void k_scan2(int* bsums, int nb) {   // single block, 512 threads
    __shared__ int s[512];
    int tid = threadIdx.x;
    int v = (tid < nb) ? bsums[tid] : 0;
    s[tid] = v;
    __syncthreads();
    for (int off = 1; off < 512; off <<= 1) {
        int t = (tid >= off) ? s[tid - off] : 0;
        __syncthreads();
        s[tid] += t;
        __syncthreads();
    }
    if (tid < nb) bsums[tid] = s[tid] - v;
}

__global__ void k_scan3(int* rowptr, const int* __restrict__ bsums, int n, int e) {
    int i = blockIdx.x * blockDim.x + threadIdx.x;
    if (i < n) {
        rowptr[i] += bsums[i >> 8];
        if (i == 0) rowptr[n] = e;
    }
}

// deterministic scatter: pos = rowptr[d] + rank[i]; no atomics.
__global__ void k_scatter(const int* __restrict__ src, const int* __restrict__ dst,
                          const float* __restrict__ ew, const float* __restrict__ dis,
                          const int* __restrict__ rowptr, const int* __restrict__ rank,
                          int2* __restrict__ em, int e) {
    int i = blockIdx.x * blockDim.x + threadIdx.x;
    if (i < e) {
        int s = src[i], d = dst[i];
        float w = dis[s] * ew[i] * dis[d];
        int pos = rowptr[d] + rank[i];
        em[pos] = make_int2(s, __float_as_int(w));
    }
}

// pull aggregation, 64 channels: one wave per node, lane = channel. unroll 4.
__global__ void k_agg64(const float* __restrict__ h, const int2* __restrict__ em,
                        const int* __restrict__ rowptr, const float* __restrict__ dis,
                        float* __restrict__ out, int n) {
    int gid = blockIdx.x * blockDim.x + threadIdx.x;
    int node = gid >> 6, lane = gid & 63;
    if (node >= n) return;
    int lo = rowptr[node], hi = rowptr[node + 1];
    float di = dis[node];
    float acc = di * di * h[(size_t)node * 64 + lane];   // self-loop
    int j = lo;
    for (; j + 3 < hi; j += 4) {
        int2 e0 = em[j], e1 = em[j + 1], e2 = em[j + 2], e3 = em[j + 3];
        float v0 = h[(size_t)e0.x * 64 + lane];
        float v1 = h[(size_t)e1.x * 64 + lane];
        float v2 = h[(size_t)e2.x * 64 + lane];
        float v3 = h[(size_t)e3.x * 64 + lane];
        acc = fmaf(__int_as_float(e0.y), v0, acc);
        acc = fmaf(__int_as_float(e1.y), v1, acc);
        acc = fmaf(__int_as_float(e2.y), v2, acc);
        acc = fmaf(__int_as_float(e3.y), v3, acc);
    }
    for (; j < hi; ++j) {
        int2 e0 = em[j];
        acc = fmaf(__int_as_float(e0.y), h[(size_t)e0.x * 64 + lane], acc);
    }
    out[(size_t)node * 64 + lane] = acc;
}

// pull aggregation, 32 channels (layer-1 input x): two edges in flight per wave.
__global__ void k_agg32(const float* __restrict__ h, const int2* __restrict__ em,
                        const int* __restrict__ rowptr, const float* __restrict__ dis,
                        float* __restrict__ out, int n) {
    int gid = blockIdx.x * blockDim.x + threadIdx.x;
    int node = gid >> 6, lane = gid & 63;
    if (node >= n) return;
    int c = lane & 31, half = lane >> 5;
    int lo = rowptr[node], hi = rowptr[node + 1];
    float di = dis[node];
    float acc = (half == 0) ? di * di * h[(size_t)node * 32 + c] : 0.0f;
    int j = lo + half;
    for (; j + 2 < hi; j += 4) {
        int2 ea = em[j], eb = em[j + 2];
        float va = h[(size_t)ea.x * 32 + c];
        float vb = h[(size_t)eb.x * 32 + c];
        acc = fmaf(__int_as_float(ea.y), va, acc);
        acc = fmaf(__int_as_float(eb.y), vb, acc);
    }
    if (j < hi) {
        int2 ev = em[j];
        acc = fmaf(__int_as_float(ev.y), h[(size_t)ev.x * 32 + c], acc);
    }
    acc += __shfl_down(acc, 32, 64);
    if (half == 0) out[(size_t)node * 32 + c] = acc;
}

// out[row,col] = silu( sum_k agg[row,k]*W[k,col] + b[col] ); W column in regs.
template <int K>
__global__ __launch_bounds__(256) void k_mm(const float* __restrict__ agg,
                                            const float* __restrict__ W,
                                            const float* __restrict__ b,
                                            float* __restrict__ out, int n) {
    int lane = threadIdx.x & 63;
    float w[K];
#pragma unroll
    for (int k = 0; k < K; ++k) w[k] = W[k * 64 + lane];
    float bias = b[lane];
    int wid = (blockIdx.x * blockDim.x + threadIdx.x) >> 6;
    int nw = (gridDim.x * blockDim.x) >> 6;
    for (int row = wid; row < n; row += nw) {
        const float* ar = agg + (size_t)row * K;
        float o = bias;
#pragma unroll
        for (int k = 0; k < K; k += 4) {
            float4 a4 = *(const float4*)(ar + k);
            o = fmaf(a4.x, w[k + 0], o);
            o = fmaf(a4.y, w[k + 1], o);
            o = fmaf(a4.z, w[k + 2], o);
            o = fmaf(a4.w, w[k + 3], o);
        }
        o = o / (1.0f + __expf(-o));
        out[(size_t)row * 64 + lane] = o;
    }
}

// --- pool phase 1: 128-row chunks, segment-flush atomics into acc[G*64] ---
// batch sorted -> per-thread strided walk sees non-decreasing graph ids.
__global__ void k_pool_partial(const float* __restrict__ h, const int* __restrict__ batch,
                               float* __restrict__ acc, int n) {
    int c = threadIdx.x & 63, r = threadIdx.x >> 6;   // 4 row-groups x 64 channels
    int base = blockIdx.x * 128;
    int end = base + 128; if (end > n) end = n;
    float part = 0.0f;
    int cur = -1;
    for (int i = base + r; i < end; i += 4) {
        int g = batch[i];
        if (g != cur) {
            if (cur >= 0) atomicAdd(&acc[cur * 64 + c], part);
            part = 0.0f;
            cur = g;
        }
        part += h[(size_t)i * 64 + c];
    }
    if (cur >= 0) atomicAdd(&acc[cur * 64 + c], part);
}

// --- pool phase 2: divide by per-graph count (binary search on sorted batch) ---
__global__ void k_pool_final(const float* __restrict__ acc, const int* __restrict__ batch,
                             float* __restrict__ out, int n) {
    int idx = blockIdx.x * blockDim.x + threadIdx.x;   // G*64 threads
    int g = idx >> 6;
    int lo = lower_bound_i(batch, n, g);
    int hi = lower_bound_i(batch, n, g + 1);
    int cnt = hi - lo;
    out[idx] = acc[idx] / (float)(cnt > 0 ? cnt : 1);
}

extern "C" void kernel_launch(void* const* d_in, const int* in_sizes, int n_in,
                              void* d_out, int out_size, void* d_ws, size_t ws_size,
                              hipStream_t stream) {
    const float* x   = (const float*)d_in[0];
    const float* ew  = (const float*)d_in[1];
    const float* W1  = (const float*)d_in[2];
    const float* b1  = (const float*)d_in[3];
    const float* W2  = (const float*)d_in[4];
    const float* b2  = (const float*)d_in[5];
    const float* W3  = (const float*)d_in[6];
    const float* b3  = (const float*)d_in[7];
    const int*   eidx  = (const int*)d_in[8];
    const int*   batch = (const int*)d_in[9];
    float* out = (float*)d_out;

    const int E = in_sizes[1];       // 1,600,000
    const int N = in_sizes[9];       // 100,000
    const int G = 64;
    const int* src = eidx;
    const int* dst = eidx + E;

    // workspace layout: A and B double as CSR-build scratch (cnt64 in A,
    // rank in B) since both are first written only after k_scatter.
    char* p = (char*)d_ws;
    float* A      = (float*)p;                 p += (size_t)N * 64 * sizeof(float);
    float* B      = (float*)p;                 p += (size_t)N * 64 * sizeof(float);
    float* dis    = (float*)p;                 p += (size_t)N * sizeof(float);
    int*   rowptr = (int*)p;                   p += (size_t)(N + 1) * sizeof(int);
    int*   bsums  = (int*)p;                   p += 1024 * sizeof(int);
    float* acc    = (float*)p;                 p += (size_t)G * 64 * sizeof(float);
    p = (char*)(((uintptr_t)p + 7) & ~(uintptr_t)7);
    int2*  em     = (int2*)p;                  // E entries, 8B each

    unsigned long long* cnt64 = (unsigned long long*)A;   // N * 8B < N*64*4B
    int* rank = (int*)B;                                  // E * 4B  < N*64*4B

    const int BT = 256;
    int gN  = (N + BT - 1) / BT;
    int gE  = (E + BT - 1) / BT;
    int gNC = (N * 64 + BT - 1) / BT;
    int nb  = gN;                              // blocks in scan1 (391 <= 512)

    // --- CSR build + normalization (shared across layers) ---
    k_zero64<<<gN, BT, 0, stream>>>(cnt64, N);
    k_hist<<<gE, BT, 0, stream>>>(dst, ew, cnt64, rank, E);
    k_unpack<<<gN, BT, 0, stream>>>(cnt64, rowptr, dis, N);
    k_scan1<<<nb, 256, 0, stream>>>(rowptr, bsums, N);
    k_scan2<<<1, 512, 0, stream>>>(bsums, nb);
    k_scan3<<<gN, BT, 0, stream>>>(rowptr, bsums, N, E);
    k_scatter<<<gE, BT, 0, stream>>>(src, dst, ew, dis, rowptr, rank, em, E);

    // --- layer 1: agg(x) [N,32] -> A ; A@W1+b1, silu -> B ---
    k_agg32<<<gNC, BT, 0, stream>>>(x, em, rowptr, dis, A, N);
    k_mm<32><<<960, BT, 0, stream>>>(A, W1, b1, B, N);

    // --- layer 2: agg(B) -> A ; A@W2+b2, silu -> B ---
    k_agg64<<<gNC, BT, 0, stream>>>(B, em, rowptr, dis, A, N);
    k_mm<64><<<960, BT, 0, stream>>>(A, W2, b2, B, N);

    // --- layer 3 ---
    k_agg64<<<gNC, BT, 0, stream>>>(B, em, rowptr, dis, A, N);
    k_mm<64><<<960, BT, 0, stream>>>(A, W3, b3, B, N);

    // --- mean pool: zero acc, partial sums, finalize ---
    hipMemsetAsync(acc, 0, (size_t)G * 64 * sizeof(float), stream);
    k_pool_partial<<<(N + 127) / 128, BT, 0, stream>>>(B, batch, acc, N);
    k_pool_final<<<(G * 64) / BT, BT, 0, stream>>>(acc, batch, out, N);
}

// Round 5
// 534.546 us; speedup vs baseline: 2.9945x; 1.0796x over previous
//
#include <hip/hip_runtime.h>
#include <math.h>

// GCN encoder, N=100000, E=1600000, C_IN=32, C_H=C_OUT=64, G=64.
// CSR build via two-level LDS counting sort (NO global atomics):
//   A1 per-block LDS bucket histogram (256 buckets x 512 nodes)
//   A2 scan (per-bucket across blocks + bucket bases)
//   A3 partition edges into dst-buckets (LDS cursors)
//   B  per-bucket: LDS packed cnt+fixp(sum ew) -> dis/rowptr/em directly.
// em weight = ew*dis[dst]; dis[src] folded into features (hs = dis*h,
// fused into matmul epilogue) so no random dis gathers anywhere.
// Pull aggregation (no float atomics), aggregate BEFORE matmul (linearity),
// matmul with register-resident W + fused bias/SiLU(+dis scale).
// Pool: two-phase partial+atomics, then finalize/divide.

#define NB   256        // dst buckets (512 nodes each; supports N < 131072)
#define PBLK 1024       // partition blocks
#define FIXP_SCALE 1048576.0f   // 2^20
#define FIXP_MASK  ((1ULL << 40) - 1)

__device__ __forceinline__ int lower_bound_i(const int* __restrict__ a, int n, int v) {
    int lo = 0, hi = n;
    while (lo < hi) {
        int m = (lo + hi) >> 1;
        if (a[m] < v) lo = m + 1; else hi = m;
    }
    return lo;
}

// A1: per-block histogram over 256 dst-buckets (LDS atomics only)
__global__ __launch_bounds__(256) void k_bhist(const int* __restrict__ dst,
                                               int* __restrict__ hcnt, int e) {
    __shared__ int hist[NB];
    int tid = threadIdx.x, blk = blockIdx.x;
    hist[tid] = 0;
    __syncthreads();
    int chunk = (e + PBLK - 1) / PBLK;
    int lo = blk * chunk, hi = min(e, lo + chunk);
    for (int i = lo + tid; i < hi; i += 256)
        atomicAdd(&hist[dst[i] >> 9], 1);
    __syncthreads();
    hcnt[tid * PBLK + blk] = hist[tid];   // [bucket][block] layout
}

// A2a: per-bucket exclusive scan across the PBLK block-counts (in place) + totals
__global__ __launch_bounds__(256) void k_bscan(int* __restrict__ hcnt,
                                               int* __restrict__ btot) {
    __shared__ int s[256];
    int b = blockIdx.x, tid = threadIdx.x;
    int* row = hcnt + b * PBLK;
    int a0 = row[4 * tid], a1 = row[4 * tid + 1], a2 = row[4 * tid + 2], a3 = row[4 * tid + 3];
    int tsum = a0 + a1 + a2 + a3;
    s[tid] = tsum;
    __syncthreads();
    for (int off = 1; off < 256; off <<= 1) {
        int t = (tid >= off) ? s[tid - off] : 0;
        __syncthreads();
        s[tid] += t;
        __syncthreads();
    }
    int ex = s[tid] - tsum;
    row[4 * tid] = ex;
    row[4 * tid + 1] = ex + a0;
    row[4 * tid + 2] = ex + a0 + a1;
    row[4 * tid + 3] = ex + a0 + a1 + a2;
    if (tid == 255) btot[b] = s[255];
}

// A2b: scan bucket totals -> bucket_base[NB+1]; also rowptr[n]=e
__global__ __launch_bounds__(256) void k_bbase(const int* __restrict__ btot,
                                               int* __restrict__ bbase,
                                               int* __restrict__ rowptr, int n, int e) {
    __shared__ int s[256];
    int tid = threadIdx.x;
    int v = btot[tid];
    s[tid] = v;
    __syncthreads();
    for (int off = 1; off < 256; off <<= 1) {
        int t = (tid >= off) ? s[tid - off] : 0;
        __syncthreads();
        s[tid] += t;
        __syncthreads();
    }
    bbase[tid] = s[tid] - v;
    if (tid == 255) bbase[NB] = s[255];   // == e
    if (tid == 0) rowptr[n] = e;
}

// A3: partition edges into buckets; pos from LDS cursor (no global atomics)
__global__ __launch_bounds__(256) void k_bpart(const int* __restrict__ src,
                                               const int* __restrict__ dst,
                                               const float* __restrict__ ew,
                                               const int* __restrict__ hcnt,
                                               const int* __restrict__ bbase,
                                               int2* __restrict__ bedge, int e) {
    __shared__ int cur[NB];
    int tid = threadIdx.x, blk = blockIdx.x;
    cur[tid] = bbase[tid] + hcnt[tid * PBLK + blk];
    __syncthreads();
    int chunk = (e + PBLK - 1) / PBLK;
    int lo = blk * chunk, hi = min(e, lo + chunk);
    for (int i = lo + tid; i < hi; i += 256) {
        int d = dst[i];
        int pos = atomicAdd(&cur[d >> 9], 1);            // LDS atomic
        bedge[pos] = make_int2(src[i] | ((d & 511) << 17), __float_as_int(ew[i]));
    }
}

// B: per-bucket (512 nodes): LDS packed cnt + fixp sum(ew) -> dis, rowptr,
// then scatter (src, ew*dis[d]) grouped per node into em. No global atomics.
__global__ __launch_bounds__(256) void k_bucket(const int2* __restrict__ bedge,
                                                const int* __restrict__ bbase,
                                                float* __restrict__ dis,
                                                int* __restrict__ rowptr,
                                                int2* __restrict__ em, int n) {
    __shared__ unsigned long long pk[512];
    __shared__ int cnt[512];
    __shared__ int scn[512];
    __shared__ float sdis[512];
    __shared__ int cur[512];
    int b = blockIdx.x, tid = threadIdx.x;
    int e0 = bbase[b], e1 = bbase[b + 1];
    pk[tid] = 0ULL; pk[tid + 256] = 0ULL;
    __syncthreads();
    for (int i = e0 + tid; i < e1; i += 256) {
        int2 v = bedge[i];
        int dlo = (v.x >> 17) & 511;
        unsigned long long p =
            (1ULL << 40) | (unsigned long long)(__int_as_float(v.y) * FIXP_SCALE);
        atomicAdd(&pk[dlo], p);                          // LDS atomic
    }
    __syncthreads();
#pragma unroll
    for (int k = 0; k < 2; ++k) {
        int i = tid + k * 256;
        unsigned long long v = pk[i];
        int c = (int)(v >> 40);
        cnt[i] = c; scn[i] = c;
        sdis[i] = rsqrtf(1.0f + (float)(v & FIXP_MASK) * (1.0f / FIXP_SCALE));
    }
    __syncthreads();
    // 512-entry inclusive scan, 2 elems/thread, read-all-then-write-all
    for (int off = 1; off < 512; off <<= 1) {
        int i0 = tid, i1 = tid + 256;
        int v0 = (i0 >= off) ? scn[i0 - off] : 0;
        int v1 = (i1 >= off) ? scn[i1 - off] : 0;
        __syncthreads();
        scn[i0] += v0; scn[i1] += v1;
        __syncthreads();
    }
#pragma unroll
    for (int k = 0; k < 2; ++k) {
        int i = tid + k * 256;
        int rb = e0 + scn[i] - cnt[i];                   // exclusive
        cur[i] = rb;
        int node = (b << 9) + i;
        if (node < n) { rowptr[node] = rb; dis[node] = sdis[i]; }
    }
    __syncthreads();
    for (int i = e0 + tid; i < e1; i += 256) {
        int2 v = bedge[i];
        int dlo = (v.x >> 17) & 511;
        int pos = atomicAdd(&cur[dlo], 1);               // LDS atomic
        float w = __int_as_float(v.y) * sdis[dlo];
        em[pos] = make_int2(v.x & 0x1FFFF, __float_as_int(w));
    }
}

// hs = dis * x  (layer-1 feature pre-scale, 32 channels)
__global__ void k_scale(const float* __restrict__ x, const float* __restrict__ dis,
                        float* __restrict__ hs, int total) {
    int idx = blockIdx.x * blockDim.x + threadIdx.x;
    if (idx < total) hs[idx] = x[idx] * dis[idx >> 5];
}

// pull aggregation, 64 channels: one wave per node, lane = channel. unroll 4.
// input h is dis-prescaled (hs); em weight includes dis[dst].
__global__ void k_agg64(const float* __restrict__ h, const int2* __restrict__ em,
                        const int* __restrict__ rowptr, const float* __restrict__ dis,
                        float* __restrict__ out, int n) {
    int gid = blockIdx.x * blockDim.x + threadIdx.x;
    int node = gid >> 6, lane = gid & 63;
    if (node >= n) return;
    int lo = rowptr[node], hi = rowptr[node + 1];
    float acc = dis[node] * h[(size_t)node * 64 + lane];   // di^2 * h = di * hs
    int j = lo;
    for (; j + 3 < hi; j += 4) {
        int2 e0 = em[j], e1 = em[j + 1], e2 = em[j + 2], e3 = em[j + 3];
        float v0 = h[(size_t)e0.x * 64 + lane];
        float v1 = h[(size_t)e1.x * 64 + lane];
        float v2 = h[(size_t)e2.x * 64 + lane];
        float v3 = h[(size_t)e3.x * 64 + lane];
        acc = fmaf(__int_as_float(e0.y), v0, acc);
        acc = fmaf(__int_as_float(e1.y), v1, acc);
        acc = fmaf(__int_as_float(e2.y), v2, acc);
        acc = fmaf(__int_as_float(e3.y), v3, acc);
    }
    for (; j < hi; ++j) {
        int2 e0 = em[j];
        acc = fmaf(__int_as_float(e0.y), h[(size_t)e0.x * 64 + lane], acc);
    }
    out[(size_t)node * 64 + lane] = acc;
}

// pull aggregation, 32 channels: two edges in flight per wave.
__global__ void k_agg32(const float* __restrict__ h, const int2* __restrict__ em,
                        const int* __restrict__ rowptr, const float* __restrict__ dis,
                        float* __restrict__ out, int n) {
    int gid = blockIdx.x * blockDim.x + threadIdx.x;
    int node = gid >> 6, lane = gid & 63;
    if (node >= n) return;
    int c = lane & 31, half = lane >> 5;
    int lo = rowptr[node], hi = rowptr[node + 1];
    float acc = (half == 0) ? dis[node] * h[(size_t)node * 32 + c] : 0.0f;
    int j = lo + half;
    for (; j + 2 < hi; j += 4) {
        int2 ea = em[j], eb = em[j + 2];
        float va = h[(size_t)ea.x * 32 + c];
        float vb = h[(size_t)eb.x * 32 + c];
        acc = fmaf(__int_as_float(ea.y), va, acc);
        acc = fmaf(__int_as_float(eb.y), vb, acc);
    }
    if (j < hi) {
        int2 ev = em[j];
        acc = fmaf(__int_as_float(ev.y), h[(size_t)ev.x * 32 + c], acc);
    }
    acc += __shfl_down(acc, 32, 64);
    if (half == 0) out[(size_t)node * 32 + c] = acc;
}

// out[row,col] = silu(sum_k agg[row,k]*W[k,col] + b[col]) * (SCALE ? dis[row] : 1)
template <int K, bool SCALE>
__global__ __launch_bounds__(256) void k_mm(const float* __restrict__ agg,
                                            const float* __restrict__ W,
                                            const float* __restrict__ b,
                                            const float* __restrict__ dis,
                                            float* __restrict__ out, int n) {
    int lane = threadIdx.x & 63;
    float w[K];
#pragma unroll
    for (int k = 0; k < K; ++k) w[k] = W[k * 64 + lane];
    float bias = b[lane];
    int wid = (blockIdx.x * blockDim.x + threadIdx.x) >> 6;
    int nw = (gridDim.x * blockDim.x) >> 6;
    for (int row = wid; row < n; row += nw) {
        const float* ar = agg + (size_t)row * K;
        float o = bias;
#pragma unroll
        for (int k = 0; k < K; k += 4) {
            float4 a4 = *(const float4*)(ar + k);
            o = fmaf(a4.x, w[k + 0], o);
            o = fmaf(a4.y, w[k + 1], o);
            o = fmaf(a4.z, w[k + 2], o);
            o = fmaf(a4.w, w[k + 3], o);
        }
        o = o / (1.0f + __expf(-o));
        if (SCALE) o *= dis[row];
        out[(size_t)row * 64 + lane] = o;
    }
}

// pool phase 1: 128-row chunks, segment-flush atomics into acc[G*64]
__global__ void k_pool_partial(const float* __restrict__ h, const int* __restrict__ batch,
                               float* __restrict__ acc, int n) {
    int c = threadIdx.x & 63, r = threadIdx.x >> 6;
    int base = blockIdx.x * 128;
    int end = base + 128; if (end > n) end = n;
    float part = 0.0f;
    int cur = -1;
    for (int i = base + r; i < end; i += 4) {
        int g = batch[i];
        if (g != cur) {
            if (cur >= 0) atomicAdd(&acc[cur * 64 + c], part);
            part = 0.0f;
            cur = g;
        }
        part += h[(size_t)i * 64 + c];
    }
    if (cur >= 0) atomicAdd(&acc[cur * 64 + c], part);
}

// pool phase 2: divide by per-graph count
__global__ void k_pool_final(const float* __restrict__ acc, const int* __restrict__ batch,
                             float* __restrict__ out, int n) {
    int idx = blockIdx.x * blockDim.x + threadIdx.x;   // G*64 threads
    int g = idx >> 6;
    int lo = lower_bound_i(batch, n, g);
    int hi = lower_bound_i(batch, n, g + 1);
    int cnt = hi - lo;
    out[idx] = acc[idx] / (float)(cnt > 0 ? cnt : 1);
}

extern "C" void kernel_launch(void* const* d_in, const int* in_sizes, int n_in,
                              void* d_out, int out_size, void* d_ws, size_t ws_size,
                              hipStream_t stream) {
    const float* x   = (const float*)d_in[0];
    const float* ew  = (const float*)d_in[1];
    const float* W1  = (const float*)d_in[2];
    const float* b1  = (const float*)d_in[3];
    const float* W2  = (const float*)d_in[4];
    const float* b2  = (const float*)d_in[5];
    const float* W3  = (const float*)d_in[6];
    const float* b3  = (const float*)d_in[7];
    const int*   eidx  = (const int*)d_in[8];
    const int*   batch = (const int*)d_in[9];
    float* out = (float*)d_out;

    const int E = in_sizes[1];       // 1,600,000
    const int N = in_sizes[9];       // 100,000 (< 131072: fits 17-bit src pack)
    const int G = 64;
    const int* src = eidx;
    const int* dst = eidx + E;

    // workspace: A/B double as CSR-build scratch (bedge in A, hcnt/btot in B),
    // both regions dead by the time features first touch them.
    char* p = (char*)d_ws;
    float* A      = (float*)p;                 p += (size_t)N * 64 * sizeof(float);
    float* B      = (float*)p;                 p += (size_t)N * 64 * sizeof(float);
    float* dis    = (float*)p;                 p += (size_t)N * sizeof(float);
    int*   rowptr = (int*)p;                   p += (size_t)(N + 1) * sizeof(int);
    int*   bbase  = (int*)p;                   p += (size_t)(NB + 1) * sizeof(int);
    float* acc    = (float*)p;                 p += (size_t)G * 64 * sizeof(float);
    p = (char*)(((uintptr_t)p + 7) & ~(uintptr_t)7);
    int2*  em     = (int2*)p;                  // E entries, 8B

    int2* bedge = (int2*)A;                    // E*8B <= N*64*4B
    int*  hcnt  = (int*)B;                     // NB*PBLK*4B = 1MB
    int*  btot  = (int*)B + NB * PBLK;         // NB ints

    const int BT = 256;
    int gNC = (N * 64 + BT - 1) / BT;

    // --- CSR build: LDS counting sort, zero global atomics ---
    k_bhist<<<PBLK, 256, 0, stream>>>(dst, hcnt, E);
    k_bscan<<<NB, 256, 0, stream>>>(hcnt, btot);
    k_bbase<<<1, 256, 0, stream>>>(btot, bbase, rowptr, N, E);
    k_bpart<<<PBLK, 256, 0, stream>>>(src, dst, ew, hcnt, bbase, bedge, E);
    k_bucket<<<NB, 256, 0, stream>>>(bedge, bbase, dis, rowptr, em, N);

    // --- layer 1: hs1 = dis*x -> A ; agg(hs1) -> B ; mm+silu*dis -> A ---
    k_scale<<<(N * 32 + BT - 1) / BT, BT, 0, stream>>>(x, dis, A, N * 32);
    k_agg32<<<gNC, BT, 0, stream>>>(A, em, rowptr, dis, B, N);
    k_mm<32, true><<<960, BT, 0, stream>>>(B, W1, b1, dis, A, N);

    // --- layer 2 ---
    k_agg64<<<gNC, BT, 0, stream>>>(A, em, rowptr, dis, B, N);
    k_mm<64, true><<<960, BT, 0, stream>>>(B, W2, b2, dis, A, N);

    // --- layer 3 (raw silu out for pooling) ---
    k_agg64<<<gNC, BT, 0, stream>>>(A, em, rowptr, dis, B, N);
    k_mm<64, false><<<960, BT, 0, stream>>>(B, W3, b3, dis, A, N);

    // --- mean pool ---
    hipMemsetAsync(acc, 0, (size_t)G * 64 * sizeof(float), stream);
    k_pool_partial<<<(N + 127) / 128, BT, 0, stream>>>(A, batch, acc, N);
    k_pool_final<<<(G * 64) / BT, BT, 0, stream>>>(acc, batch, out, N);
}

// Round 6
// 463.746 us; speedup vs baseline: 3.4517x; 1.1527x over previous
//
#include <hip/hip_runtime.h>
#include <math.h>

// GCN encoder, N=100000, E=1600000, C_IN=32, C_H=C_OUT=64, G=64.
// CSR build via two-level LDS counting sort (NO global atomics).
// em weight = ew*dis[dst]; dis[src] folded into features.
// R6: aggregation FUSED with matmul+bias+SiLU(+dis prescale for next layer):
//   per wave: gather-accumulate acc[lane] over edge list, broadcast acc via
//   per-wave LDS slot (float4 reads, same-addr broadcast = conflict-free),
//   matvec against register-resident W column (w[64] loaded once per wave,
//   amortized over 8 grid-strided rows), silu epilogue, one store.
// Pool: two-phase partial+atomics, then finalize/divide.

#define NB   256        // dst buckets (512 nodes each; supports N < 131072)
#define PBLK 1024       // partition blocks
#define FIXP_SCALE 1048576.0f   // 2^20
#define FIXP_MASK  ((1ULL << 40) - 1)

__device__ __forceinline__ int lower_bound_i(const int* __restrict__ a, int n, int v) {
    int lo = 0, hi = n;
    while (lo < hi) {
        int m = (lo + hi) >> 1;
        if (a[m] < v) lo = m + 1; else hi = m;
    }
    return lo;
}

// A1: per-block histogram over 256 dst-buckets (LDS atomics only)
__global__ __launch_bounds__(256) void k_bhist(const int* __restrict__ dst,
                                               int* __restrict__ hcnt, int e) {
    __shared__ int hist[NB];
    int tid = threadIdx.x, blk = blockIdx.x;
    hist[tid] = 0;
    __syncthreads();
    int chunk = (e + PBLK - 1) / PBLK;
    int lo = blk * chunk, hi = min(e, lo + chunk);
    for (int i = lo + tid; i < hi; i += 256)
        atomicAdd(&hist[dst[i] >> 9], 1);
    __syncthreads();
    hcnt[tid * PBLK + blk] = hist[tid];   // [bucket][block] layout
}

// A2a: per-bucket exclusive scan across the PBLK block-counts (in place) + totals
__global__ __launch_bounds__(256) void k_bscan(int* __restrict__ hcnt,
                                               int* __restrict__ btot) {
    __shared__ int s[256];
    int b = blockIdx.x, tid = threadIdx.x;
    int* row = hcnt + b * PBLK;
    int a0 = row[4 * tid], a1 = row[4 * tid + 1], a2 = row[4 * tid + 2], a3 = row[4 * tid + 3];
    int tsum = a0 + a1 + a2 + a3;
    s[tid] = tsum;
    __syncthreads();
    for (int off = 1; off < 256; off <<= 1) {
        int t = (tid >= off) ? s[tid - off] : 0;
        __syncthreads();
        s[tid] += t;
        __syncthreads();
    }
    int ex = s[tid] - tsum;
    row[4 * tid] = ex;
    row[4 * tid + 1] = ex + a0;
    row[4 * tid + 2] = ex + a0 + a1;
    row[4 * tid + 3] = ex + a0 + a1 + a2;
    if (tid == 255) btot[b] = s[255];
}

// A2b: scan bucket totals -> bucket_base[NB+1]; also rowptr[n]=e
__global__ __launch_bounds__(256) void k_bbase(const int* __restrict__ btot,
                                               int* __restrict__ bbase,
                                               int* __restrict__ rowptr, int n, int e) {
    __shared__ int s[256];
    int tid = threadIdx.x;
    int v = btot[tid];
    s[tid] = v;
    __syncthreads();
    for (int off = 1; off < 256; off <<= 1) {
        int t = (tid >= off) ? s[tid - off] : 0;
        __syncthreads();
        s[tid] += t;
        __syncthreads();
    }
    bbase[tid] = s[tid] - v;
    if (tid == 255) bbase[NB] = s[255];   // == e
    if (tid == 0) rowptr[n] = e;
}

// A3: partition edges into buckets; pos from LDS cursor (no global atomics)
__global__ __launch_bounds__(256) void k_bpart(const int* __restrict__ src,
                                               const int* __restrict__ dst,
                                               const float* __restrict__ ew,
                                               const int* __restrict__ hcnt,
                                               const int* __restrict__ bbase,
                                               int2* __restrict__ bedge, int e) {
    __shared__ int cur[NB];
    int tid = threadIdx.x, blk = blockIdx.x;
    cur[tid] = bbase[tid] + hcnt[tid * PBLK + blk];
    __syncthreads();
    int chunk = (e + PBLK - 1) / PBLK;
    int lo = blk * chunk, hi = min(e, lo + chunk);
    for (int i = lo + tid; i < hi; i += 256) {
        int d = dst[i];
        int pos = atomicAdd(&cur[d >> 9], 1);            // LDS atomic
        bedge[pos] = make_int2(src[i] | ((d & 511) << 17), __float_as_int(ew[i]));
    }
}

// B: per-bucket (512 nodes): LDS packed cnt + fixp sum(ew) -> dis, rowptr,
// then scatter (src, ew*dis[d]) grouped per node into em. No global atomics.
__global__ __launch_bounds__(256) void k_bucket(const int2* __restrict__ bedge,
                                                const int* __restrict__ bbase,
                                                float* __restrict__ dis,
                                                int* __restrict__ rowptr,
                                                int2* __restrict__ em, int n) {
    __shared__ unsigned long long pk[512];
    __shared__ int cnt[512];
    __shared__ int scn[512];
    __shared__ float sdis[512];
    __shared__ int cur[512];
    int b = blockIdx.x, tid = threadIdx.x;
    int e0 = bbase[b], e1 = bbase[b + 1];
    pk[tid] = 0ULL; pk[tid + 256] = 0ULL;
    __syncthreads();
    for (int i = e0 + tid; i < e1; i += 256) {
        int2 v = bedge[i];
        int dlo = (v.x >> 17) & 511;
        unsigned long long p =
            (1ULL << 40) | (unsigned long long)(__int_as_float(v.y) * FIXP_SCALE);
        atomicAdd(&pk[dlo], p);                          // LDS atomic
    }
    __syncthreads();
#pragma unroll
    for (int k = 0; k < 2; ++k) {
        int i = tid + k * 256;
        unsigned long long v = pk[i];
        int c = (int)(v >> 40);
        cnt[i] = c; scn[i] = c;
        sdis[i] = rsqrtf(1.0f + (float)(v & FIXP_MASK) * (1.0f / FIXP_SCALE));
    }
    __syncthreads();
    // 512-entry inclusive scan, 2 elems/thread, read-all-then-write-all
    for (int off = 1; off < 512; off <<= 1) {
        int i0 = tid, i1 = tid + 256;
        int v0 = (i0 >= off) ? scn[i0 - off] : 0;
        int v1 = (i1 >= off) ? scn[i1 - off] : 0;
        __syncthreads();
        scn[i0] += v0; scn[i1] += v1;
        __syncthreads();
    }
#pragma unroll
    for (int k = 0; k < 2; ++k) {
        int i = tid + k * 256;
        int rb = e0 + scn[i] - cnt[i];                   // exclusive
        cur[i] = rb;
        int node = (b << 9) + i;
        if (node < n) { rowptr[node] = rb; dis[node] = sdis[i]; }
    }
    __syncthreads();
    for (int i = e0 + tid; i < e1; i += 256) {
        int2 v = bedge[i];
        int dlo = (v.x >> 17) & 511;
        int pos = atomicAdd(&cur[dlo], 1);               // LDS atomic
        float w = __int_as_float(v.y) * sdis[dlo];
        em[pos] = make_int2(v.x & 0x1FFFF, __float_as_int(w));
    }
}

// hs = dis * x  (layer-1 feature pre-scale, 32 channels)
__global__ void k_scale(const float* __restrict__ x, const float* __restrict__ dis,
                        float* __restrict__ hs, int total) {
    int idx = blockIdx.x * blockDim.x + threadIdx.x;
    if (idx < total) hs[idx] = x[idx] * dis[idx >> 5];
}

// Fused: pull-aggregate (64-ch, dis-prescaled h, em weight has dis[dst]) then
// per-wave 64x64 matvec (acc broadcast via per-wave LDS slot, W column in
// regs, loaded once per wave and amortized over grid-strided rows), then
// bias+SiLU(+dis prescale for next layer's gather). One store per row.
template <bool SCALE>
__global__ __launch_bounds__(256) void k_aggmm64(const float* __restrict__ h,
                                                 const int2* __restrict__ em,
                                                 const int* __restrict__ rowptr,
                                                 const float* __restrict__ dis,
                                                 const float* __restrict__ W,
                                                 const float* __restrict__ bias,
                                                 float* __restrict__ out, int n) {
    __shared__ __align__(16) float sacc[4][64];
    int lane = threadIdx.x & 63, wv = threadIdx.x >> 6;
    float w[64];
#pragma unroll
    for (int k = 0; k < 64; ++k) w[k] = W[k * 64 + lane];
    float bv = bias[lane];
    int wid = (blockIdx.x * blockDim.x + threadIdx.x) >> 6;
    int nw = (gridDim.x * blockDim.x) >> 6;
    for (int node = wid; node < n; node += nw) {
        int lo = rowptr[node], hi = rowptr[node + 1];
        float acc = dis[node] * h[(size_t)node * 64 + lane];   // di^2*h = di*hs
        int j = lo;
        for (; j + 3 < hi; j += 4) {
            int2 e0 = em[j], e1 = em[j + 1], e2 = em[j + 2], e3 = em[j + 3];
            float v0 = h[(size_t)e0.x * 64 + lane];
            float v1 = h[(size_t)e1.x * 64 + lane];
            float v2 = h[(size_t)e2.x * 64 + lane];
            float v3 = h[(size_t)e3.x * 64 + lane];
            acc = fmaf(__int_as_float(e0.y), v0, acc);
            acc = fmaf(__int_as_float(e1.y), v1, acc);
            acc = fmaf(__int_as_float(e2.y), v2, acc);
            acc = fmaf(__int_as_float(e3.y), v3, acc);
        }
        for (; j < hi; ++j) {
            int2 e0 = em[j];
            acc = fmaf(__int_as_float(e0.y), h[(size_t)e0.x * 64 + lane], acc);
        }
        // matvec: o[lane] = b + sum_k acc_k * W[k][lane]
        sacc[wv][lane] = acc;
        float o = bv;
        const float4* s4 = (const float4*)sacc[wv];
#pragma unroll
        for (int k4 = 0; k4 < 16; ++k4) {
            float4 a4 = s4[k4];                 // same addr all lanes: broadcast
            o = fmaf(a4.x, w[4 * k4 + 0], o);
            o = fmaf(a4.y, w[4 * k4 + 1], o);
            o = fmaf(a4.z, w[4 * k4 + 2], o);
            o = fmaf(a4.w, w[4 * k4 + 3], o);
        }
        o = o / (1.0f + __expf(-o));
        if (SCALE) o *= dis[node];
        out[(size_t)node * 64 + lane] = o;
    }
}

// Fused layer-1: 32-ch aggregate (two edges in flight across wave halves),
// then 32x64 matvec + bias + SiLU + dis prescale.
__global__ __launch_bounds__(256) void k_aggmm32(const float* __restrict__ h,
                                                 const int2* __restrict__ em,
                                                 const int* __restrict__ rowptr,
                                                 const float* __restrict__ dis,
                                                 const float* __restrict__ W,
                                                 const float* __restrict__ bias,
                                                 float* __restrict__ out, int n) {
    __shared__ __align__(16) float sacc[4][32];
    int lane = threadIdx.x & 63, wv = threadIdx.x >> 6;
    int c = lane & 31, half = lane >> 5;
    float w[32];
#pragma unroll
    for (int k = 0; k < 32; ++k) w[k] = W[k * 64 + lane];
    float bv = bias[lane];
    int wid = (blockIdx.x * blockDim.x + threadIdx.x) >> 6;
    int nw = (gridDim.x * blockDim.x) >> 6;
    for (int node = wid; node < n; node += nw) {
        int lo = rowptr[node], hi = rowptr[node + 1];
        float acc = (half == 0) ? dis[node] * h[(size_t)node * 32 + c] : 0.0f;
        int j = lo + half;
        for (; j + 2 < hi; j += 4) {
            int2 ea = em[j], eb = em[j + 2];
            float va = h[(size_t)ea.x * 32 + c];
            float vb = h[(size_t)eb.x * 32 + c];
            acc = fmaf(__int_as_float(ea.y), va, acc);
            acc = fmaf(__int_as_float(eb.y), vb, acc);
        }
        if (j < hi) {
            int2 ev = em[j];
            acc = fmaf(__int_as_float(ev.y), h[(size_t)ev.x * 32 + c], acc);
        }
        acc += __shfl_down(acc, 32, 64);
        if (half == 0) sacc[wv][c] = acc;
        float o = bv;
        const float4* s4 = (const float4*)sacc[wv];
#pragma unroll
        for (int k4 = 0; k4 < 8; ++k4) {
            float4 a4 = s4[k4];
            o = fmaf(a4.x, w[4 * k4 + 0], o);
            o = fmaf(a4.y, w[4 * k4 + 1], o);
            o = fmaf(a4.z, w[4 * k4 + 2], o);
            o = fmaf(a4.w, w[4 * k4 + 3], o);
        }
        o = o / (1.0f + __expf(-o));
        o *= dis[node];
        out[(size_t)node * 64 + lane] = o;
    }
}

// pool phase 1: 128-row chunks, segment-flush atomics into acc[G*64]
__global__ void k_pool_partial(const float* __restrict__ h, const int* __restrict__ batch,
                               float* __restrict__ acc, int n) {
    int c = threadIdx.x & 63, r = threadIdx.x >> 6;
    int base = blockIdx.x * 128;
    int end = base + 128; if (end > n) end = n;
    float part = 0.0f;
    int cur = -1;
    for (int i = base + r; i < end; i += 4) {
        int g = batch[i];
        if (g != cur) {
            if (cur >= 0) atomicAdd(&acc[cur * 64 + c], part);
            part = 0.0f;
            cur = g;
        }
        part += h[(size_t)i * 64 + c];
    }
    if (cur >= 0) atomicAdd(&acc[cur * 64 + c], part);
}

// pool phase 2: divide by per-graph count
__global__ void k_pool_final(const float* __restrict__ acc, const int* __restrict__ batch,
                             float* __restrict__ out, int n) {
    int idx = blockIdx.x * blockDim.x + threadIdx.x;   // G*64 threads
    int g = idx >> 6;
    int lo = lower_bound_i(batch, n, g);
    int hi = lower_bound_i(batch, n, g + 1);
    int cnt = hi - lo;
    out[idx] = acc[idx] / (float)(cnt > 0 ? cnt : 1);
}

extern "C" void kernel_launch(void* const* d_in, const int* in_sizes, int n_in,
                              void* d_out, int out_size, void* d_ws, size_t ws_size,
                              hipStream_t stream) {
    const float* x   = (const float*)d_in[0];
    const float* ew  = (const float*)d_in[1];
    const float* W1  = (const float*)d_in[2];
    const float* b1  = (const float*)d_in[3];
    const float* W2  = (const float*)d_in[4];
    const float* b2  = (const float*)d_in[5];
    const float* W3  = (const float*)d_in[6];
    const float* b3  = (const float*)d_in[7];
    const int*   eidx  = (const int*)d_in[8];
    const int*   batch = (const int*)d_in[9];
    float* out = (float*)d_out;

    const int E = in_sizes[1];       // 1,600,000
    const int N = in_sizes[9];       // 100,000 (< 131072: fits 17-bit src pack)
    const int G = 64;
    const int* src = eidx;
    const int* dst = eidx + E;

    // workspace: A/B double as CSR-build scratch (bedge in A, hcnt/btot in B),
    // both regions dead by the time features first touch them.
    char* p = (char*)d_ws;
    float* A      = (float*)p;                 p += (size_t)N * 64 * sizeof(float);
    float* B      = (float*)p;                 p += (size_t)N * 64 * sizeof(float);
    float* dis    = (float*)p;                 p += (size_t)N * sizeof(float);
    int*   rowptr = (int*)p;                   p += (size_t)(N + 1) * sizeof(int);
    int*   bbase  = (int*)p;                   p += (size_t)(NB + 1) * sizeof(int);
    float* acc    = (float*)p;                 p += (size_t)G * 64 * sizeof(float);
    p = (char*)(((uintptr_t)p + 7) & ~(uintptr_t)7);
    int2*  em     = (int2*)p;                  // E entries, 8B

    int2* bedge = (int2*)A;                    // E*8B <= N*64*4B
    int*  hcnt  = (int*)B;                     // NB*PBLK*4B = 1MB
    int*  btot  = (int*)B + NB * PBLK;         // NB ints

    const int BT = 256;
    const int FUSED_BLOCKS = 3125;             // 12500 waves x 8 rows = 100k

    // --- CSR build: LDS counting sort, zero global atomics ---
    k_bhist<<<PBLK, 256, 0, stream>>>(dst, hcnt, E);
    k_bscan<<<NB, 256, 0, stream>>>(hcnt, btot);
    k_bbase<<<1, 256, 0, stream>>>(btot, bbase, rowptr, N, E);
    k_bpart<<<PBLK, 256, 0, stream>>>(src, dst, ew, hcnt, bbase, bedge, E);
    k_bucket<<<NB, 256, 0, stream>>>(bedge, bbase, dis, rowptr, em, N);

    // --- layer 1: hs1 = dis*x -> A ; fused agg+mm+silu*dis -> B ---
    k_scale<<<(N * 32 + BT - 1) / BT, BT, 0, stream>>>(x, dis, A, N * 32);
    k_aggmm32<<<FUSED_BLOCKS, BT, 0, stream>>>(A, em, rowptr, dis, W1, b1, B, N);

    // --- layer 2: fused agg+mm+silu*dis -> A ---
    k_aggmm64<true><<<FUSED_BLOCKS, BT, 0, stream>>>(B, em, rowptr, dis, W2, b2, A, N);

    // --- layer 3: fused agg+mm+silu (raw, for pooling) -> B ---
    k_aggmm64<false><<<FUSED_BLOCKS, BT, 0, stream>>>(A, em, rowptr, dis, W3, b3, B, N);

    // --- mean pool ---
    hipMemsetAsync(acc, 0, (size_t)G * 64 * sizeof(float), stream);
    k_pool_partial<<<(N + 127) / 128, BT, 0, stream>>>(B, batch, acc, N);
    k_pool_final<<<(G * 64) / BT, BT, 0, stream>>>(acc, batch, out, N);
}

// Round 7
// 396.423 us; speedup vs baseline: 4.0379x; 1.1698x over previous
//
#include <hip/hip_runtime.h>
#include <math.h>

// GCN encoder, N=100000, E=1600000, C_IN=32, C_H=C_OUT=64, G=64.
// CSR build via two-level LDS counting sort (NO global atomics).
// em weight = ew*dis[dst]; dis[src] folded into features.
// Fused agg+matmul+bias+SiLU per layer. R7: (a) __launch_bounds__(256,4) so
// the register-resident W column truly stays in VGPRs; (b) wave-batched em
// staging (1 coalesced load / 64 edges) + constant-index __shfl broadcast
// (v_readlane) so all h[src] gathers in a 16-edge chunk are independent.

#define NB   256        // dst buckets (512 nodes each; supports N < 131072)
#define PBLK 1024       // partition blocks
#define FIXP_SCALE 1048576.0f   // 2^20
#define FIXP_MASK  ((1ULL << 40) - 1)

__device__ __forceinline__ int lower_bound_i(const int* __restrict__ a, int n, int v) {
    int lo = 0, hi = n;
    while (lo < hi) {
        int m = (lo + hi) >> 1;
        if (a[m] < v) lo = m + 1; else hi = m;
    }
    return lo;
}

// A1: per-block histogram over 256 dst-buckets (LDS atomics only)
__global__ __launch_bounds__(256) void k_bhist(const int* __restrict__ dst,
                                               int* __restrict__ hcnt, int e) {
    __shared__ int hist[NB];
    int tid = threadIdx.x, blk = blockIdx.x;
    hist[tid] = 0;
    __syncthreads();
    int chunk = (e + PBLK - 1) / PBLK;
    int lo = blk * chunk, hi = min(e, lo + chunk);
    for (int i = lo + tid; i < hi; i += 256)
        atomicAdd(&hist[dst[i] >> 9], 1);
    __syncthreads();
    hcnt[tid * PBLK + blk] = hist[tid];   // [bucket][block] layout
}

// A2a: per-bucket exclusive scan across the PBLK block-counts (in place) + totals
__global__ __launch_bounds__(256) void k_bscan(int* __restrict__ hcnt,
                                               int* __restrict__ btot) {
    __shared__ int s[256];
    int b = blockIdx.x, tid = threadIdx.x;
    int* row = hcnt + b * PBLK;
    int a0 = row[4 * tid], a1 = row[4 * tid + 1], a2 = row[4 * tid + 2], a3 = row[4 * tid + 3];
    int tsum = a0 + a1 + a2 + a3;
    s[tid] = tsum;
    __syncthreads();
    for (int off = 1; off < 256; off <<= 1) {
        int t = (tid >= off) ? s[tid - off] : 0;
        __syncthreads();
        s[tid] += t;
        __syncthreads();
    }
    int ex = s[tid] - tsum;
    row[4 * tid] = ex;
    row[4 * tid + 1] = ex + a0;
    row[4 * tid + 2] = ex + a0 + a1;
    row[4 * tid + 3] = ex + a0 + a1 + a2;
    if (tid == 255) btot[b] = s[255];
}

// A2b: scan bucket totals -> bucket_base[NB+1]; also rowptr[n]=e
__global__ __launch_bounds__(256) void k_bbase(const int* __restrict__ btot,
                                               int* __restrict__ bbase,
                                               int* __restrict__ rowptr, int n, int e) {
    __shared__ int s[256];
    int tid = threadIdx.x;
    int v = btot[tid];
    s[tid] = v;
    __syncthreads();
    for (int off = 1; off < 256; off <<= 1) {
        int t = (tid >= off) ? s[tid - off] : 0;
        __syncthreads();
        s[tid] += t;
        __syncthreads();
    }
    bbase[tid] = s[tid] - v;
    if (tid == 255) bbase[NB] = s[255];   // == e
    if (tid == 0) rowptr[n] = e;
}

// A3: partition edges into buckets; pos from LDS cursor (no global atomics)
__global__ __launch_bounds__(256) void k_bpart(const int* __restrict__ src,
                                               const int* __restrict__ dst,
                                               const float* __restrict__ ew,
                                               const int* __restrict__ hcnt,
                                               const int* __restrict__ bbase,
                                               int2* __restrict__ bedge, int e) {
    __shared__ int cur[NB];
    int tid = threadIdx.x, blk = blockIdx.x;
    cur[tid] = bbase[tid] + hcnt[tid * PBLK + blk];
    __syncthreads();
    int chunk = (e + PBLK - 1) / PBLK;
    int lo = blk * chunk, hi = min(e, lo + chunk);
    for (int i = lo + tid; i < hi; i += 256) {
        int d = dst[i];
        int pos = atomicAdd(&cur[d >> 9], 1);            // LDS atomic
        bedge[pos] = make_int2(src[i] | ((d & 511) << 17), __float_as_int(ew[i]));
    }
}

// B: per-bucket (512 nodes): LDS packed cnt + fixp sum(ew) -> dis, rowptr,
// then scatter (src, ew*dis[d]) grouped per node into em. No global atomics.
__global__ __launch_bounds__(256) void k_bucket(const int2* __restrict__ bedge,
                                                const int* __restrict__ bbase,
                                                float* __restrict__ dis,
                                                int* __restrict__ rowptr,
                                                int2* __restrict__ em, int n) {
    __shared__ unsigned long long pk[512];
    __shared__ int cnt[512];
    __shared__ int scn[512];
    __shared__ float sdis[512];
    __shared__ int cur[512];
    int b = blockIdx.x, tid = threadIdx.x;
    int e0 = bbase[b], e1 = bbase[b + 1];
    pk[tid] = 0ULL; pk[tid + 256] = 0ULL;
    __syncthreads();
    for (int i = e0 + tid; i < e1; i += 256) {
        int2 v = bedge[i];
        int dlo = (v.x >> 17) & 511;
        unsigned long long p =
            (1ULL << 40) | (unsigned long long)(__int_as_float(v.y) * FIXP_SCALE);
        atomicAdd(&pk[dlo], p);                          // LDS atomic
    }
    __syncthreads();
#pragma unroll
    for (int k = 0; k < 2; ++k) {
        int i = tid + k * 256;
        unsigned long long v = pk[i];
        int c = (int)(v >> 40);
        cnt[i] = c; scn[i] = c;
        sdis[i] = rsqrtf(1.0f + (float)(v & FIXP_MASK) * (1.0f / FIXP_SCALE));
    }
    __syncthreads();
    // 512-entry inclusive scan, 2 elems/thread, read-all-then-write-all
    for (int off = 1; off < 512; off <<= 1) {
        int i0 = tid, i1 = tid + 256;
        int v0 = (i0 >= off) ? scn[i0 - off] : 0;
        int v1 = (i1 >= off) ? scn[i1 - off] : 0;
        __syncthreads();
        scn[i0] += v0; scn[i1] += v1;
        __syncthreads();
    }
#pragma unroll
    for (int k = 0; k < 2; ++k) {
        int i = tid + k * 256;
        int rb = e0 + scn[i] - cnt[i];                   // exclusive
        cur[i] = rb;
        int node = (b << 9) + i;
        if (node < n) { rowptr[node] = rb; dis[node] = sdis[i]; }
    }
    __syncthreads();
    for (int i = e0 + tid; i < e1; i += 256) {
        int2 v = bedge[i];
        int dlo = (v.x >> 17) & 511;
        int pos = atomicAdd(&cur[dlo], 1);               // LDS atomic
        float w = __int_as_float(v.y) * sdis[dlo];
        em[pos] = make_int2(v.x & 0x1FFFF, __float_as_int(w));
    }
}

// hs = dis * x  (layer-1 feature pre-scale, 32 channels)
__global__ void k_scale(const float* __restrict__ x, const float* __restrict__ dis,
                        float* __restrict__ hs, int total) {
    int idx = blockIdx.x * blockDim.x + threadIdx.x;
    if (idx < total) hs[idx] = x[idx] * dis[idx >> 5];
}

// Fused agg + 64x64 matvec + bias + SiLU (+dis prescale).
// Gather: wave stages 64 em entries (1 coalesced load), broadcasts via
// constant-index shfl (v_readlane); padded lanes carry w=0 so the unrolled
// 16-chunks need no per-edge bounds checks.
template <bool SCALE>
__global__ __launch_bounds__(256, 4) void k_aggmm64(const float* __restrict__ h,
                                                    const int2* __restrict__ em,
                                                    const int* __restrict__ rowptr,
                                                    const float* __restrict__ dis,
                                                    const float* __restrict__ W,
                                                    const float* __restrict__ bias,
                                                    float* __restrict__ out, int n) {
    __shared__ __align__(16) float sacc[4][64];
    int lane = threadIdx.x & 63, wv = threadIdx.x >> 6;
    float w[64];
#pragma unroll
    for (int k = 0; k < 64; ++k) w[k] = W[k * 64 + lane];
    float bv = bias[lane];
    int wid = (blockIdx.x * blockDim.x + threadIdx.x) >> 6;
    int nw = (gridDim.x * blockDim.x) >> 6;
    for (int node = wid; node < n; node += nw) {
        int lo = rowptr[node], hi = rowptr[node + 1];
        int deg = hi - lo;
        float acc = dis[node] * h[(size_t)node * 64 + lane];   // di^2*h = di*hs
        for (int jb = 0; jb < deg; jb += 64) {
            int idx = lo + jb + lane;
            int2 me = (idx < hi) ? em[idx] : make_int2(0, 0);  // w=0 pad
            int rem = deg - jb;
#pragma unroll
            for (int g = 0; g < 4; ++g) {
                if (g * 16 < rem) {
#pragma unroll
                    for (int t = 0; t < 16; ++t) {
                        int s = __shfl(me.x, g * 16 + t, 64);
                        float ww = __int_as_float(__shfl(me.y, g * 16 + t, 64));
                        acc = fmaf(ww, h[(size_t)s * 64 + lane], acc);
                    }
                }
            }
        }
        // matvec: o[lane] = b + sum_k acc_k * W[k][lane]
        sacc[wv][lane] = acc;
        float o = bv;
        const float4* s4 = (const float4*)sacc[wv];
#pragma unroll
        for (int k4 = 0; k4 < 16; ++k4) {
            float4 a4 = s4[k4];                 // same addr all lanes: broadcast
            o = fmaf(a4.x, w[4 * k4 + 0], o);
            o = fmaf(a4.y, w[4 * k4 + 1], o);
            o = fmaf(a4.z, w[4 * k4 + 2], o);
            o = fmaf(a4.w, w[4 * k4 + 3], o);
        }
        o = o / (1.0f + __expf(-o));
        if (SCALE) o *= dis[node];
        out[(size_t)node * 64 + lane] = o;
    }
}

// Fused layer-1 (32-ch input): halves of the wave process even/odd edges from
// the staged batch (dynamic shfl = bpermute), then cross-half reduce, then
// 32x64 matvec + bias + SiLU + dis prescale.
__global__ __launch_bounds__(256, 4) void k_aggmm32(const float* __restrict__ h,
                                                    const int2* __restrict__ em,
                                                    const int* __restrict__ rowptr,
                                                    const float* __restrict__ dis,
                                                    const float* __restrict__ W,
                                                    const float* __restrict__ bias,
                                                    float* __restrict__ out, int n) {
    __shared__ __align__(16) float sacc[4][32];
    int lane = threadIdx.x & 63, wv = threadIdx.x >> 6;
    int c = lane & 31, half = lane >> 5;
    float w[32];
#pragma unroll
    for (int k = 0; k < 32; ++k) w[k] = W[k * 64 + lane];
    float bv = bias[lane];
    int wid = (blockIdx.x * blockDim.x + threadIdx.x) >> 6;
    int nw = (gridDim.x * blockDim.x) >> 6;
    for (int node = wid; node < n; node += nw) {
        int lo = rowptr[node], hi = rowptr[node + 1];
        int deg = hi - lo;
        float acc = (half == 0) ? dis[node] * h[(size_t)node * 32 + c] : 0.0f;
        for (int jb = 0; jb < deg; jb += 64) {
            int idx = lo + jb + lane;
            int2 me = (idx < hi) ? em[idx] : make_int2(0, 0);  // w=0 pad
            int rem = deg - jb;
#pragma unroll
            for (int g = 0; g < 4; ++g) {
                if (g * 16 < rem) {
#pragma unroll
                    for (int t = 0; t < 8; ++t) {
                        int ei = g * 16 + 2 * t + half;        // per-half edge
                        int s = __shfl(me.x, ei, 64);
                        float ww = __int_as_float(__shfl(me.y, ei, 64));
                        acc = fmaf(ww, h[(size_t)s * 32 + c], acc);
                    }
                }
            }
        }
        acc += __shfl_down(acc, 32, 64);
        if (half == 0) sacc[wv][c] = acc;
        float o = bv;
        const float4* s4 = (const float4*)sacc[wv];
#pragma unroll
        for (int k4 = 0; k4 < 8; ++k4) {
            float4 a4 = s4[k4];
            o = fmaf(a4.x, w[4 * k4 + 0], o);
            o = fmaf(a4.y, w[4 * k4 + 1], o);
            o = fmaf(a4.z, w[4 * k4 + 2], o);
            o = fmaf(a4.w, w[4 * k4 + 3], o);
        }
        o = o / (1.0f + __expf(-o));
        o *= dis[node];
        out[(size_t)node * 64 + lane] = o;
    }
}

// pool phase 1: 128-row chunks, segment-flush atomics into acc[G*64]
__global__ void k_pool_partial(const float* __restrict__ h, const int* __restrict__ batch,
                               float* __restrict__ acc, int n) {
    int c = threadIdx.x & 63, r = threadIdx.x >> 6;
    int base = blockIdx.x * 128;
    int end = base + 128; if (end > n) end = n;
    float part = 0.0f;
    int cur = -1;
    for (int i = base + r; i < end; i += 4) {
        int g = batch[i];
        if (g != cur) {
            if (cur >= 0) atomicAdd(&acc[cur * 64 + c], part);
            part = 0.0f;
            cur = g;
        }
        part += h[(size_t)i * 64 + c];
    }
    if (cur >= 0) atomicAdd(&acc[cur * 64 + c], part);
}

// pool phase 2: divide by per-graph count
__global__ void k_pool_final(const float* __restrict__ acc, const int* __restrict__ batch,
                             float* __restrict__ out, int n) {
    int idx = blockIdx.x * blockDim.x + threadIdx.x;   // G*64 threads
    int g = idx >> 6;
    int lo = lower_bound_i(batch, n, g);
    int hi = lower_bound_i(batch, n, g + 1);
    int cnt = hi - lo;
    out[idx] = acc[idx] / (float)(cnt > 0 ? cnt : 1);
}

extern "C" void kernel_launch(void* const* d_in, const int* in_sizes, int n_in,
                              void* d_out, int out_size, void* d_ws, size_t ws_size,
                              hipStream_t stream) {
    const float* x   = (const float*)d_in[0];
    const float* ew  = (const float*)d_in[1];
    const float* W1  = (const float*)d_in[2];
    const float* b1  = (const float*)d_in[3];
    const float* W2  = (const float*)d_in[4];
    const float* b2  = (const float*)d_in[5];
    const float* W3  = (const float*)d_in[6];
    const float* b3  = (const float*)d_in[7];
    const int*   eidx  = (const int*)d_in[8];
    const int*   batch = (const int*)d_in[9];
    float* out = (float*)d_out;

    const int E = in_sizes[1];       // 1,600,000
    const int N = in_sizes[9];       // 100,000 (< 131072: fits 17-bit src pack)
    const int G = 64;
    const int* src = eidx;
    const int* dst = eidx + E;

    // workspace: A/B double as CSR-build scratch (bedge in A, hcnt/btot in B),
    // both regions dead by the time features first touch them.
    char* p = (char*)d_ws;
    float* A      = (float*)p;                 p += (size_t)N * 64 * sizeof(float);
    float* B      = (float*)p;                 p += (size_t)N * 64 * sizeof(float);
    float* dis    = (float*)p;                 p += (size_t)N * sizeof(float);
    int*   rowptr = (int*)p;                   p += (size_t)(N + 1) * sizeof(int);
    int*   bbase  = (int*)p;                   p += (size_t)(NB + 1) * sizeof(int);
    float* acc    = (float*)p;                 p += (size_t)G * 64 * sizeof(float);
    p = (char*)(((uintptr_t)p + 7) & ~(uintptr_t)7);
    int2*  em     = (int2*)p;                  // E entries, 8B

    int2* bedge = (int2*)A;                    // E*8B <= N*64*4B
    int*  hcnt  = (int*)B;                     // NB*PBLK*4B = 1MB
    int*  btot  = (int*)B + NB * PBLK;         // NB ints

    const int BT = 256;
    const int FUSED_BLOCKS = 3125;             // 12500 waves x 8 rows = 100k

    // --- CSR build: LDS counting sort, zero global atomics ---
    k_bhist<<<PBLK, 256, 0, stream>>>(dst, hcnt, E);
    k_bscan<<<NB, 256, 0, stream>>>(hcnt, btot);
    k_bbase<<<1, 256, 0, stream>>>(btot, bbase, rowptr, N, E);
    k_bpart<<<PBLK, 256, 0, stream>>>(src, dst, ew, hcnt, bbase, bedge, E);
    k_bucket<<<NB, 256, 0, stream>>>(bedge, bbase, dis, rowptr, em, N);

    // --- layer 1: hs1 = dis*x -> A ; fused agg+mm+silu*dis -> B ---
    k_scale<<<(N * 32 + BT - 1) / BT, BT, 0, stream>>>(x, dis, A, N * 32);
    k_aggmm32<<<FUSED_BLOCKS, BT, 0, stream>>>(A, em, rowptr, dis, W1, b1, B, N);

    // --- layer 2: fused agg+mm+silu*dis -> A ---
    k_aggmm64<true><<<FUSED_BLOCKS, BT, 0, stream>>>(B, em, rowptr, dis, W2, b2, A, N);

    // --- layer 3: fused agg+mm+silu (raw, for pooling) -> B ---
    k_aggmm64<false><<<FUSED_BLOCKS, BT, 0, stream>>>(A, em, rowptr, dis, W3, b3, B, N);

    // --- mean pool ---
    hipMemsetAsync(acc, 0, (size_t)G * 64 * sizeof(float), stream);
    k_pool_partial<<<(N + 127) / 128, BT, 0, stream>>>(B, batch, acc, N);
    k_pool_final<<<(G * 64) / BT, BT, 0, stream>>>(acc, batch, out, N);
}

// Round 8
// 386.212 us; speedup vs baseline: 4.1446x; 1.0264x over previous
//
#include <hip/hip_runtime.h>
#include <hip/hip_fp16.h>
#include <math.h>

// GCN encoder, N=100000, E=1600000, C_IN=32, C_H=C_OUT=64, G=64.
// CSR build via two-level LDS counting sort (NO global atomics).
// em weight = ew*dis[dst]; dis[src] folded into features.
// Fused agg+matmul+bias+SiLU per layer; wave-batched em staging +
// constant-index shfl broadcast for independent gathers.
// R8: inter-layer features stored FP16 (halves gather traffic, the dominant
// cost); accumulate/matvec/W/bias stay FP32; final layer writes FP32.

#define NB   256        // dst buckets (512 nodes each; supports N < 131072)
#define PBLK 1024       // partition blocks
#define FIXP_SCALE 1048576.0f   // 2^20
#define FIXP_MASK  ((1ULL << 40) - 1)

__device__ __forceinline__ int lower_bound_i(const int* __restrict__ a, int n, int v) {
    int lo = 0, hi = n;
    while (lo < hi) {
        int m = (lo + hi) >> 1;
        if (a[m] < v) lo = m + 1; else hi = m;
    }
    return lo;
}

// A1: per-block histogram over 256 dst-buckets (LDS atomics only)
__global__ __launch_bounds__(256) void k_bhist(const int* __restrict__ dst,
                                               int* __restrict__ hcnt, int e) {
    __shared__ int hist[NB];
    int tid = threadIdx.x, blk = blockIdx.x;
    hist[tid] = 0;
    __syncthreads();
    int chunk = (e + PBLK - 1) / PBLK;
    int lo = blk * chunk, hi = min(e, lo + chunk);
    for (int i = lo + tid; i < hi; i += 256)
        atomicAdd(&hist[dst[i] >> 9], 1);
    __syncthreads();
    hcnt[tid * PBLK + blk] = hist[tid];   // [bucket][block] layout
}

// A2a: per-bucket exclusive scan across the PBLK block-counts (in place) + totals
__global__ __launch_bounds__(256) void k_bscan(int* __restrict__ hcnt,
                                               int* __restrict__ btot) {
    __shared__ int s[256];
    int b = blockIdx.x, tid = threadIdx.x;
    int* row = hcnt + b * PBLK;
    int a0 = row[4 * tid], a1 = row[4 * tid + 1], a2 = row[4 * tid + 2], a3 = row[4 * tid + 3];
    int tsum = a0 + a1 + a2 + a3;
    s[tid] = tsum;
    __syncthreads();
    for (int off = 1; off < 256; off <<= 1) {
        int t = (tid >= off) ? s[tid - off] : 0;
        __syncthreads();
        s[tid] += t;
        __syncthreads();
    }
    int ex = s[tid] - tsum;
    row[4 * tid] = ex;
    row[4 * tid + 1] = ex + a0;
    row[4 * tid + 2] = ex + a0 + a1;
    row[4 * tid + 3] = ex + a0 + a1 + a2;
    if (tid == 255) btot[b] = s[255];
}

// A2b: scan bucket totals -> bucket_base[NB+1]; also rowptr[n]=e
__global__ __launch_bounds__(256) void k_bbase(const int* __restrict__ btot,
                                               int* __restrict__ bbase,
                                               int* __restrict__ rowptr, int n, int e) {
    __shared__ int s[256];
    int tid = threadIdx.x;
    int v = btot[tid];
    s[tid] = v;
    __syncthreads();
    for (int off = 1; off < 256; off <<= 1) {
        int t = (tid >= off) ? s[tid - off] : 0;
        __syncthreads();
        s[tid] += t;
        __syncthreads();
    }
    bbase[tid] = s[tid] - v;
    if (tid == 255) bbase[NB] = s[255];   // == e
    if (tid == 0) rowptr[n] = e;
}

// A3: partition edges into buckets; pos from LDS cursor (no global atomics)
__global__ __launch_bounds__(256) void k_bpart(const int* __restrict__ src,
                                               const int* __restrict__ dst,
                                               const float* __restrict__ ew,
                                               const int* __restrict__ hcnt,
                                               const int* __restrict__ bbase,
                                               int2* __restrict__ bedge, int e) {
    __shared__ int cur[NB];
    int tid = threadIdx.x, blk = blockIdx.x;
    cur[tid] = bbase[tid] + hcnt[tid * PBLK + blk];
    __syncthreads();
    int chunk = (e + PBLK - 1) / PBLK;
    int lo = blk * chunk, hi = min(e, lo + chunk);
    for (int i = lo + tid; i < hi; i += 256) {
        int d = dst[i];
        int pos = atomicAdd(&cur[d >> 9], 1);            // LDS atomic
        bedge[pos] = make_int2(src[i] | ((d & 511) << 17), __float_as_int(ew[i]));
    }
}

// B: per-bucket (512 nodes): LDS packed cnt + fixp sum(ew) -> dis, rowptr,
// then scatter (src, ew*dis[d]) grouped per node into em. No global atomics.
__global__ __launch_bounds__(256) void k_bucket(const int2* __restrict__ bedge,
                                                const int* __restrict__ bbase,
                                                float* __restrict__ dis,
                                                int* __restrict__ rowptr,
                                                int2* __restrict__ em, int n) {
    __shared__ unsigned long long pk[512];
    __shared__ int cnt[512];
    __shared__ int scn[512];
    __shared__ float sdis[512];
    __shared__ int cur[512];
    int b = blockIdx.x, tid = threadIdx.x;
    int e0 = bbase[b], e1 = bbase[b + 1];
    pk[tid] = 0ULL; pk[tid + 256] = 0ULL;
    __syncthreads();
    for (int i = e0 + tid; i < e1; i += 256) {
        int2 v = bedge[i];
        int dlo = (v.x >> 17) & 511;
        unsigned long long p =
            (1ULL << 40) | (unsigned long long)(__int_as_float(v.y) * FIXP_SCALE);
        atomicAdd(&pk[dlo], p);                          // LDS atomic
    }
    __syncthreads();
#pragma unroll
    for (int k = 0; k < 2; ++k) {
        int i = tid + k * 256;
        unsigned long long v = pk[i];
        int c = (int)(v >> 40);
        cnt[i] = c; scn[i] = c;
        sdis[i] = rsqrtf(1.0f + (float)(v & FIXP_MASK) * (1.0f / FIXP_SCALE));
    }
    __syncthreads();
    // 512-entry inclusive scan, 2 elems/thread, read-all-then-write-all
    for (int off = 1; off < 512; off <<= 1) {
        int i0 = tid, i1 = tid + 256;
        int v0 = (i0 >= off) ? scn[i0 - off] : 0;
        int v1 = (i1 >= off) ? scn[i1 - off] : 0;
        __syncthreads();
        scn[i0] += v0; scn[i1] += v1;
        __syncthreads();
    }
#pragma unroll
    for (int k = 0; k < 2; ++k) {
        int i = tid + k * 256;
        int rb = e0 + scn[i] - cnt[i];                   // exclusive
        cur[i] = rb;
        int node = (b << 9) + i;
        if (node < n) { rowptr[node] = rb; dis[node] = sdis[i]; }
    }
    __syncthreads();
    for (int i = e0 + tid; i < e1; i += 256) {
        int2 v = bedge[i];
        int dlo = (v.x >> 17) & 511;
        int pos = atomicAdd(&cur[dlo], 1);               // LDS atomic
        float w = __int_as_float(v.y) * sdis[dlo];
        em[pos] = make_int2(v.x & 0x1FFFF, __float_as_int(w));
    }
}

// hs = fp16(dis * x)  (layer-1 feature pre-scale, 32 channels)
__global__ void k_scale(const float* __restrict__ x, const float* __restrict__ dis,
                        __half* __restrict__ hs, int total) {
    int idx = blockIdx.x * blockDim.x + threadIdx.x;
    if (idx < total) hs[idx] = __float2half(x[idx] * dis[idx >> 5]);
}

// Fused agg + 64x64 matvec + bias + SiLU (+dis prescale). FP16 features in;
// OUT = __half (intermediate layers) or float (final layer).
template <bool SCALE, typename OUT>
__global__ __launch_bounds__(256, 4) void k_aggmm64(const __half* __restrict__ h,
                                                    const int2* __restrict__ em,
                                                    const int* __restrict__ rowptr,
                                                    const float* __restrict__ dis,
                                                    const float* __restrict__ W,
                                                    const float* __restrict__ bias,
                                                    OUT* __restrict__ out, int n) {
    __shared__ __align__(16) float sacc[4][64];
    int lane = threadIdx.x & 63, wv = threadIdx.x >> 6;
    float w[64];
#pragma unroll
    for (int k = 0; k < 64; ++k) w[k] = W[k * 64 + lane];
    float bv = bias[lane];
    int wid = (blockIdx.x * blockDim.x + threadIdx.x) >> 6;
    int nw = (gridDim.x * blockDim.x) >> 6;
    for (int node = wid; node < n; node += nw) {
        int lo = rowptr[node], hi = rowptr[node + 1];
        int deg = hi - lo;
        float acc = dis[node] * __half2float(h[(size_t)node * 64 + lane]);
        for (int jb = 0; jb < deg; jb += 64) {
            int idx = lo + jb + lane;
            int2 me = (idx < hi) ? em[idx] : make_int2(0, 0);  // w=0 pad
            int rem = deg - jb;
#pragma unroll
            for (int g = 0; g < 4; ++g) {
                if (g * 16 < rem) {
#pragma unroll
                    for (int t = 0; t < 16; ++t) {
                        int s = __shfl(me.x, g * 16 + t, 64);
                        float ww = __int_as_float(__shfl(me.y, g * 16 + t, 64));
                        acc = fmaf(ww, __half2float(h[(size_t)s * 64 + lane]), acc);
                    }
                }
            }
        }
        // matvec: o[lane] = b + sum_k acc_k * W[k][lane]
        sacc[wv][lane] = acc;
        float o = bv;
        const float4* s4 = (const float4*)sacc[wv];
#pragma unroll
        for (int k4 = 0; k4 < 16; ++k4) {
            float4 a4 = s4[k4];                 // same addr all lanes: broadcast
            o = fmaf(a4.x, w[4 * k4 + 0], o);
            o = fmaf(a4.y, w[4 * k4 + 1], o);
            o = fmaf(a4.z, w[4 * k4 + 2], o);
            o = fmaf(a4.w, w[4 * k4 + 3], o);
        }
        o = o / (1.0f + __expf(-o));
        if (SCALE) o *= dis[node];
        if (sizeof(OUT) == 2) {
            ((__half*)out)[(size_t)node * 64 + lane] = __float2half(o);
        } else {
            ((float*)out)[(size_t)node * 64 + lane] = o;
        }
    }
}

// Fused layer-1 (32-ch fp16 input): halves of the wave process even/odd edges
// from the staged batch, cross-half reduce, 32x64 matvec + bias + SiLU + dis.
__global__ __launch_bounds__(256, 4) void k_aggmm32(const __half* __restrict__ h,
                                                    const int2* __restrict__ em,
                                                    const int* __restrict__ rowptr,
                                                    const float* __restrict__ dis,
                                                    const float* __restrict__ W,
                                                    const float* __restrict__ bias,
                                                    __half* __restrict__ out, int n) {
    __shared__ __align__(16) float sacc[4][32];
    int lane = threadIdx.x & 63, wv = threadIdx.x >> 6;
    int c = lane & 31, half = lane >> 5;
    float w[32];
#pragma unroll
    for (int k = 0; k < 32; ++k) w[k] = W[k * 64 + lane];
    float bv = bias[lane];
    int wid = (blockIdx.x * blockDim.x + threadIdx.x) >> 6;
    int nw = (gridDim.x * blockDim.x) >> 6;
    for (int node = wid; node < n; node += nw) {
        int lo = rowptr[node], hi = rowptr[node + 1];
        int deg = hi - lo;
        float acc = (half == 0) ? dis[node] * __half2float(h[(size_t)node * 32 + c]) : 0.0f;
        for (int jb = 0; jb < deg; jb += 64) {
            int idx = lo + jb + lane;
            int2 me = (idx < hi) ? em[idx] : make_int2(0, 0);  // w=0 pad
            int rem = deg - jb;
#pragma unroll
            for (int g = 0; g < 4; ++g) {
                if (g * 16 < rem) {
#pragma unroll
                    for (int t = 0; t < 8; ++t) {
                        int ei = g * 16 + 2 * t + half;        // per-half edge
                        int s = __shfl(me.x, ei, 64);
                        float ww = __int_as_float(__shfl(me.y, ei, 64));
                        acc = fmaf(ww, __half2float(h[(size_t)s * 32 + c]), acc);
                    }
                }
            }
        }
        acc += __shfl_down(acc, 32, 64);
        if (half == 0) sacc[wv][c] = acc;
        float o = bv;
        const float4* s4 = (const float4*)sacc[wv];
#pragma unroll
        for (int k4 = 0; k4 < 8; ++k4) {
            float4 a4 = s4[k4];
            o = fmaf(a4.x, w[4 * k4 + 0], o);
            o = fmaf(a4.y, w[4 * k4 + 1], o);
            o = fmaf(a4.z, w[4 * k4 + 2], o);
            o = fmaf(a4.w, w[4 * k4 + 3], o);
        }
        o = o / (1.0f + __expf(-o));
        o *= dis[node];
        out[(size_t)node * 64 + lane] = __float2half(o);
    }
}

// pool phase 1: 128-row chunks, segment-flush atomics into acc[G*64]
__global__ void k_pool_partial(const float* __restrict__ h, const int* __restrict__ batch,
                               float* __restrict__ acc, int n) {
    int c = threadIdx.x & 63, r = threadIdx.x >> 6;
    int base = blockIdx.x * 128;
    int end = base + 128; if (end > n) end = n;
    float part = 0.0f;
    int cur = -1;
    for (int i = base + r; i < end; i += 4) {
        int g = batch[i];
        if (g != cur) {
            if (cur >= 0) atomicAdd(&acc[cur * 64 + c], part);
            part = 0.0f;
            cur = g;
        }
        part += h[(size_t)i * 64 + c];
    }
    if (cur >= 0) atomicAdd(&acc[cur * 64 + c], part);
}

// pool phase 2: divide by per-graph count
__global__ void k_pool_final(const float* __restrict__ acc, const int* __restrict__ batch,
                             float* __restrict__ out, int n) {
    int idx = blockIdx.x * blockDim.x + threadIdx.x;   // G*64 threads
    int g = idx >> 6;
    int lo = lower_bound_i(batch, n, g);
    int hi = lower_bound_i(batch, n, g + 1);
    int cnt = hi - lo;
    out[idx] = acc[idx] / (float)(cnt > 0 ? cnt : 1);
}

extern "C" void kernel_launch(void* const* d_in, const int* in_sizes, int n_in,
                              void* d_out, int out_size, void* d_ws, size_t ws_size,
                              hipStream_t stream) {
    const float* x   = (const float*)d_in[0];
    const float* ew  = (const float*)d_in[1];
    const float* W1  = (const float*)d_in[2];
    const float* b1  = (const float*)d_in[3];
    const float* W2  = (const float*)d_in[4];
    const float* b2  = (const float*)d_in[5];
    const float* W3  = (const float*)d_in[6];
    const float* b3  = (const float*)d_in[7];
    const int*   eidx  = (const int*)d_in[8];
    const int*   batch = (const int*)d_in[9];
    float* out = (float*)d_out;

    const int E = in_sizes[1];       // 1,600,000
    const int N = in_sizes[9];       // 100,000 (< 131072: fits 17-bit src pack)
    const int G = 64;
    const int* src = eidx;
    const int* dst = eidx + E;

    // workspace: A/B (fp16 features) double as CSR-build scratch
    // (bedge in A: E*8B == N*64*2B exactly; hcnt/btot in B), both dead by the
    // time features first touch them. C holds the final fp32 layer for pooling.
    char* p = (char*)d_ws;
    __half* A     = (__half*)p;                p += (size_t)N * 64 * sizeof(__half);
    __half* B     = (__half*)p;                p += (size_t)N * 64 * sizeof(__half);
    float* C      = (float*)p;                 p += (size_t)N * 64 * sizeof(float);
    float* dis    = (float*)p;                 p += (size_t)N * sizeof(float);
    int*   rowptr = (int*)p;                   p += (size_t)(N + 1) * sizeof(int);
    int*   bbase  = (int*)p;                   p += (size_t)(NB + 1) * sizeof(int);
    float* acc    = (float*)p;                 p += (size_t)G * 64 * sizeof(float);
    p = (char*)(((uintptr_t)p + 7) & ~(uintptr_t)7);
    int2*  em     = (int2*)p;                  // E entries, 8B

    int2* bedge = (int2*)A;                    // E*8B == N*64*2B
    int*  hcnt  = (int*)B;                     // NB*PBLK*4B = 1MB
    int*  btot  = (int*)B + NB * PBLK;         // NB ints

    const int BT = 256;
    const int FUSED_BLOCKS = 3125;             // 12500 waves x 8 rows = 100k

    // --- CSR build: LDS counting sort, zero global atomics ---
    k_bhist<<<PBLK, 256, 0, stream>>>(dst, hcnt, E);
    k_bscan<<<NB, 256, 0, stream>>>(hcnt, btot);
    k_bbase<<<1, 256, 0, stream>>>(btot, bbase, rowptr, N, E);
    k_bpart<<<PBLK, 256, 0, stream>>>(src, dst, ew, hcnt, bbase, bedge, E);
    k_bucket<<<NB, 256, 0, stream>>>(bedge, bbase, dis, rowptr, em, N);

    // --- layer 1: hs1 = fp16(dis*x) -> B ; fused agg+mm+silu*dis -> A ---
    // (B's hcnt scratch is dead after k_bpart; A's bedge dead after k_bucket)
    k_scale<<<(N * 32 + BT - 1) / BT, BT, 0, stream>>>(x, dis, (__half*)B, N * 32);
    k_aggmm32<<<FUSED_BLOCKS, BT, 0, stream>>>((__half*)B, em, rowptr, dis, W1, b1, A, N);

    // --- layer 2: fused agg+mm+silu*dis -> B ---
    k_aggmm64<true, __half><<<FUSED_BLOCKS, BT, 0, stream>>>(A, em, rowptr, dis, W2, b2, B, N);

    // --- layer 3: fused agg+mm+silu (raw fp32, for pooling) -> C ---
    k_aggmm64<false, float><<<FUSED_BLOCKS, BT, 0, stream>>>(B, em, rowptr, dis, W3, b3, C, N);

    // --- mean pool ---
    hipMemsetAsync(acc, 0, (size_t)G * 64 * sizeof(float), stream);
    k_pool_partial<<<(N + 127) / 128, BT, 0, stream>>>(C, batch, acc, N);
    k_pool_final<<<(G * 64) / BT, BT, 0, stream>>>(acc, batch, out, N);
}

// Round 9
// 349.086 us; speedup vs baseline: 4.5854x; 1.1064x over previous
//
#include <hip/hip_runtime.h>
#include <hip/hip_fp16.h>
#include <math.h>

// GCN encoder, N=100000, E=1600000, C_IN=32, C_H=C_OUT=64, G=64.
// CSR build via two-level LDS counting sort (NO global atomics).
// em weight = ew*dis[dst]; dis[src] folded into features.
// Fused agg+matmul+bias+SiLU per layer. FP16 features.
// R9: pair-gather — fp16 channel-pair per lane, wave halves process two
// edges per gather instruction (layer1: quarters, 4 edges/instr); edge
// metadata staged in LDS, read back with per-half uniform ds_read_b64
// (2-way broadcast = conflict-free). Halves vmem+VALU per edge.

#define NB   256        // dst buckets (512 nodes each; supports N < 131072)
#define PBLK 1024       // partition blocks
#define FIXP_SCALE 1048576.0f   // 2^20
#define FIXP_MASK  ((1ULL << 40) - 1)

__device__ __forceinline__ int lower_bound_i(const int* __restrict__ a, int n, int v) {
    int lo = 0, hi = n;
    while (lo < hi) {
        int m = (lo + hi) >> 1;
        if (a[m] < v) lo = m + 1; else hi = m;
    }
    return lo;
}

// A1: per-block histogram over 256 dst-buckets (LDS atomics only)
__global__ __launch_bounds__(256) void k_bhist(const int* __restrict__ dst,
                                               int* __restrict__ hcnt, int e) {
    __shared__ int hist[NB];
    int tid = threadIdx.x, blk = blockIdx.x;
    hist[tid] = 0;
    __syncthreads();
    int chunk = (e + PBLK - 1) / PBLK;
    int lo = blk * chunk, hi = min(e, lo + chunk);
    for (int i = lo + tid; i < hi; i += 256)
        atomicAdd(&hist[dst[i] >> 9], 1);
    __syncthreads();
    hcnt[tid * PBLK + blk] = hist[tid];   // [bucket][block] layout
}

// A2a: per-bucket exclusive scan across the PBLK block-counts (in place) + totals
__global__ __launch_bounds__(256) void k_bscan(int* __restrict__ hcnt,
                                               int* __restrict__ btot) {
    __shared__ int s[256];
    int b = blockIdx.x, tid = threadIdx.x;
    int* row = hcnt + b * PBLK;
    int a0 = row[4 * tid], a1 = row[4 * tid + 1], a2 = row[4 * tid + 2], a3 = row[4 * tid + 3];
    int tsum = a0 + a1 + a2 + a3;
    s[tid] = tsum;
    __syncthreads();
    for (int off = 1; off < 256; off <<= 1) {
        int t = (tid >= off) ? s[tid - off] : 0;
        __syncthreads();
        s[tid] += t;
        __syncthreads();
    }
    int ex = s[tid] - tsum;
    row[4 * tid] = ex;
    row[4 * tid + 1] = ex + a0;
    row[4 * tid + 2] = ex + a0 + a1;
    row[4 * tid + 3] = ex + a0 + a1 + a2;
    if (tid == 255) btot[b] = s[255];
}

// A2b: scan bucket totals -> bucket_base[NB+1]; also rowptr[n]=e
__global__ __launch_bounds__(256) void k_bbase(const int* __restrict__ btot,
                                               int* __restrict__ bbase,
                                               int* __restrict__ rowptr, int n, int e) {
    __shared__ int s[256];
    int tid = threadIdx.x;
    int v = btot[tid];
    s[tid] = v;
    __syncthreads();
    for (int off = 1; off < 256; off <<= 1) {
        int t = (tid >= off) ? s[tid - off] : 0;
        __syncthreads();
        s[tid] += t;
        __syncthreads();
    }
    bbase[tid] = s[tid] - v;
    if (tid == 255) bbase[NB] = s[255];   // == e
    if (tid == 0) rowptr[n] = e;
}

// A3: partition edges into buckets; pos from LDS cursor (no global atomics)
__global__ __launch_bounds__(256) void k_bpart(const int* __restrict__ src,
                                               const int* __restrict__ dst,
                                               const float* __restrict__ ew,
                                               const int* __restrict__ hcnt,
                                               const int* __restrict__ bbase,
                                               int2* __restrict__ bedge, int e) {
    __shared__ int cur[NB];
    int tid = threadIdx.x, blk = blockIdx.x;
    cur[tid] = bbase[tid] + hcnt[tid * PBLK + blk];
    __syncthreads();
    int chunk = (e + PBLK - 1) / PBLK;
    int lo = blk * chunk, hi = min(e, lo + chunk);
    for (int i = lo + tid; i < hi; i += 256) {
        int d = dst[i];
        int pos = atomicAdd(&cur[d >> 9], 1);            // LDS atomic
        bedge[pos] = make_int2(src[i] | ((d & 511) << 17), __float_as_int(ew[i]));
    }
}

// B: per-bucket (512 nodes): LDS packed cnt + fixp sum(ew) -> dis, rowptr,
// then scatter (src, ew*dis[d]) grouped per node into em. No global atomics.
__global__ __launch_bounds__(256) void k_bucket(const int2* __restrict__ bedge,
                                                const int* __restrict__ bbase,
                                                float* __restrict__ dis,
                                                int* __restrict__ rowptr,
                                                int2* __restrict__ em, int n) {
    __shared__ unsigned long long pk[512];
    __shared__ int cnt[512];
    __shared__ int scn[512];
    __shared__ float sdis[512];
    __shared__ int cur[512];
    int b = blockIdx.x, tid = threadIdx.x;
    int e0 = bbase[b], e1 = bbase[b + 1];
    pk[tid] = 0ULL; pk[tid + 256] = 0ULL;
    __syncthreads();
    for (int i = e0 + tid; i < e1; i += 256) {
        int2 v = bedge[i];
        int dlo = (v.x >> 17) & 511;
        unsigned long long p =
            (1ULL << 40) | (unsigned long long)(__int_as_float(v.y) * FIXP_SCALE);
        atomicAdd(&pk[dlo], p);                          // LDS atomic
    }
    __syncthreads();
#pragma unroll
    for (int k = 0; k < 2; ++k) {
        int i = tid + k * 256;
        unsigned long long v = pk[i];
        int c = (int)(v >> 40);
        cnt[i] = c; scn[i] = c;
        sdis[i] = rsqrtf(1.0f + (float)(v & FIXP_MASK) * (1.0f / FIXP_SCALE));
    }
    __syncthreads();
    // 512-entry inclusive scan, 2 elems/thread, read-all-then-write-all
    for (int off = 1; off < 512; off <<= 1) {
        int i0 = tid, i1 = tid + 256;
        int v0 = (i0 >= off) ? scn[i0 - off] : 0;
        int v1 = (i1 >= off) ? scn[i1 - off] : 0;
        __syncthreads();
        scn[i0] += v0; scn[i1] += v1;
        __syncthreads();
    }
#pragma unroll
    for (int k = 0; k < 2; ++k) {
        int i = tid + k * 256;
        int rb = e0 + scn[i] - cnt[i];                   // exclusive
        cur[i] = rb;
        int node = (b << 9) + i;
        if (node < n) { rowptr[node] = rb; dis[node] = sdis[i]; }
    }
    __syncthreads();
    for (int i = e0 + tid; i < e1; i += 256) {
        int2 v = bedge[i];
        int dlo = (v.x >> 17) & 511;
        int pos = atomicAdd(&cur[dlo], 1);               // LDS atomic
        float w = __int_as_float(v.y) * sdis[dlo];
        em[pos] = make_int2(v.x & 0x1FFFF, __float_as_int(w));
    }
}

// hs = fp16(dis * x)  (layer-1 feature pre-scale, 32 channels)
__global__ void k_scale(const float* __restrict__ x, const float* __restrict__ dis,
                        __half* __restrict__ hs, int total) {
    int idx = blockIdx.x * blockDim.x + threadIdx.x;
    if (idx < total) hs[idx] = __float2half(x[idx] * dis[idx >> 5]);
}

__device__ __forceinline__ float2 cvt_pair(unsigned int u) {
    __half2 h2 = *(__half2*)&u;
    return __half22float2(h2);
}

// Fused agg + 64x64 matvec + bias + SiLU (+dis prescale). FP16 features.
// Pair-gather: lane = channel-pair c (uint load = 2 fp16), wave halves take
// even/odd edges -> one gather instruction covers 2 edges. Edge meta staged
// in LDS, per-half uniform ds_read_b64 (broadcast).
template <bool SCALE, typename OUT>
__global__ __launch_bounds__(256, 4) void k_aggmm64(const __half* __restrict__ h,
                                                    const int2* __restrict__ em,
                                                    const int* __restrict__ rowptr,
                                                    const float* __restrict__ dis,
                                                    const float* __restrict__ W,
                                                    const float* __restrict__ bias,
                                                    OUT* __restrict__ out, int n) {
    __shared__ __align__(16) float sacc[4][64];
    __shared__ __align__(8) int2 sme[4][64];
    int lane = threadIdx.x & 63, wv = threadIdx.x >> 6;
    int c = lane & 31, half = lane >> 5;
    const unsigned int* h32 = (const unsigned int*)h;
    float w[64];
#pragma unroll
    for (int k = 0; k < 64; ++k) w[k] = W[k * 64 + lane];
    float bv = bias[lane];
    int wid = (blockIdx.x * blockDim.x + threadIdx.x) >> 6;
    int nw = (gridDim.x * blockDim.x) >> 6;
    for (int node = wid; node < n; node += nw) {
        int lo = rowptr[node], hi = rowptr[node + 1];
        int deg = hi - lo;
        float2 acc = make_float2(0.0f, 0.0f);
        if (half == 0) {
            float2 hv = cvt_pair(h32[(size_t)node * 32 + c]);
            float di = dis[node];
            acc.x = di * hv.x; acc.y = di * hv.y;        // di^2*h = di*hs
        }
        for (int jb = 0; jb < deg; jb += 64) {
            int idx = lo + jb + lane;
            int2 me = (idx < hi) ? em[idx] : make_int2(0, 0);  // w=0 pad
            sme[wv][lane] = me;
            int rem = deg - jb;
#pragma unroll
            for (int g = 0; g < 4; ++g) {
                if (g * 16 < rem) {
#pragma unroll
                    for (int t = 0; t < 8; ++t) {
                        int2 ev = sme[wv][g * 16 + 2 * t + half];  // per-half bcast
                        float ww = __int_as_float(ev.y);
                        float2 hf = cvt_pair(h32[(size_t)ev.x * 32 + c]);
                        acc.x = fmaf(ww, hf.x, acc.x);
                        acc.y = fmaf(ww, hf.y, acc.y);
                    }
                }
            }
        }
        // cross-half reduce, then channel-pair layout into sacc
        acc.x += __shfl_down(acc.x, 32, 64);
        acc.y += __shfl_down(acc.y, 32, 64);
        if (half == 0) ((float2*)sacc[wv])[c] = acc;     // floats 2c, 2c+1
        float o = bv;
        const float4* s4 = (const float4*)sacc[wv];
#pragma unroll
        for (int k4 = 0; k4 < 16; ++k4) {
            float4 a4 = s4[k4];                 // same addr all lanes: broadcast
            o = fmaf(a4.x, w[4 * k4 + 0], o);
            o = fmaf(a4.y, w[4 * k4 + 1], o);
            o = fmaf(a4.z, w[4 * k4 + 2], o);
            o = fmaf(a4.w, w[4 * k4 + 3], o);
        }
        o = o / (1.0f + __expf(-o));
        if (SCALE) o *= dis[node];
        if (sizeof(OUT) == 2) {
            ((__half*)out)[(size_t)node * 64 + lane] = __float2half(o);
        } else {
            ((float*)out)[(size_t)node * 64 + lane] = o;
        }
    }
}

// Fused layer-1 (32-ch fp16 input): lane = channel-pair c (16 dwords/row),
// wave quarters take edges mod 4 -> 4 edges per gather instruction.
__global__ __launch_bounds__(256, 4) void k_aggmm32(const __half* __restrict__ h,
                                                    const int2* __restrict__ em,
                                                    const int* __restrict__ rowptr,
                                                    const float* __restrict__ dis,
                                                    const float* __restrict__ W,
                                                    const float* __restrict__ bias,
                                                    __half* __restrict__ out, int n) {
    __shared__ __align__(16) float sacc[4][32];
    __shared__ __align__(8) int2 sme[4][64];
    int lane = threadIdx.x & 63, wv = threadIdx.x >> 6;
    int c = lane & 15, quarter = lane >> 4;
    const unsigned int* h32 = (const unsigned int*)h;
    float w[32];
#pragma unroll
    for (int k = 0; k < 32; ++k) w[k] = W[k * 64 + lane];
    float bv = bias[lane];
    int wid = (blockIdx.x * blockDim.x + threadIdx.x) >> 6;
    int nw = (gridDim.x * blockDim.x) >> 6;
    for (int node = wid; node < n; node += nw) {
        int lo = rowptr[node], hi = rowptr[node + 1];
        int deg = hi - lo;
        float2 acc = make_float2(0.0f, 0.0f);
        if (quarter == 0) {
            float2 hv = cvt_pair(h32[(size_t)node * 16 + c]);
            float di = dis[node];
            acc.x = di * hv.x; acc.y = di * hv.y;
        }
        for (int jb = 0; jb < deg; jb += 64) {
            int idx = lo + jb + lane;
            int2 me = (idx < hi) ? em[idx] : make_int2(0, 0);  // w=0 pad
            sme[wv][lane] = me;
            int rem = deg - jb;
#pragma unroll
            for (int g = 0; g < 4; ++g) {
                if (g * 16 < rem) {
#pragma unroll
                    for (int t = 0; t < 4; ++t) {
                        int2 ev = sme[wv][g * 16 + 4 * t + quarter];  // per-quarter bcast
                        float ww = __int_as_float(ev.y);
                        float2 hf = cvt_pair(h32[(size_t)ev.x * 16 + c]);
                        acc.x = fmaf(ww, hf.x, acc.x);
                        acc.y = fmaf(ww, hf.y, acc.y);
                    }
                }
            }
        }
        // cross-quarter reduce (q0+=q2, q1+=q3; then q0+=q1)
        acc.x += __shfl_down(acc.x, 32, 64);
        acc.y += __shfl_down(acc.y, 32, 64);
        acc.x += __shfl_down(acc.x, 16, 64);
        acc.y += __shfl_down(acc.y, 16, 64);
        if (quarter == 0) ((float2*)sacc[wv])[c] = acc;  // floats 2c, 2c+1
        float o = bv;
        const float4* s4 = (const float4*)sacc[wv];
#pragma unroll
        for (int k4 = 0; k4 < 8; ++k4) {
            float4 a4 = s4[k4];
            o = fmaf(a4.x, w[4 * k4 + 0], o);
            o = fmaf(a4.y, w[4 * k4 + 1], o);
            o = fmaf(a4.z, w[4 * k4 + 2], o);
            o = fmaf(a4.w, w[4 * k4 + 3], o);
        }
        o = o / (1.0f + __expf(-o));
        o *= dis[node];
        out[(size_t)node * 64 + lane] = __float2half(o);
    }
}

// pool phase 1: 128-row chunks, segment-flush atomics into acc[G*64]
__global__ void k_pool_partial(const float* __restrict__ h, const int* __restrict__ batch,
                               float* __restrict__ acc, int n) {
    int c = threadIdx.x & 63, r = threadIdx.x >> 6;
    int base = blockIdx.x * 128;
    int end = base + 128; if (end > n) end = n;
    float part = 0.0f;
    int cur = -1;
    for (int i = base + r; i < end; i += 4) {
        int g = batch[i];
        if (g != cur) {
            if (cur >= 0) atomicAdd(&acc[cur * 64 + c], part);
            part = 0.0f;
            cur = g;
        }
        part += h[(size_t)i * 64 + c];
    }
    if (cur >= 0) atomicAdd(&acc[cur * 64 + c], part);
}

// pool phase 2: divide by per-graph count
__global__ void k_pool_final(const float* __restrict__ acc, const int* __restrict__ batch,
                             float* __restrict__ out, int n) {
    int idx = blockIdx.x * blockDim.x + threadIdx.x;   // G*64 threads
    int g = idx >> 6;
    int lo = lower_bound_i(batch, n, g);
    int hi = lower_bound_i(batch, n, g + 1);
    int cnt = hi - lo;
    out[idx] = acc[idx] / (float)(cnt > 0 ? cnt : 1);
}

extern "C" void kernel_launch(void* const* d_in, const int* in_sizes, int n_in,
                              void* d_out, int out_size, void* d_ws, size_t ws_size,
                              hipStream_t stream) {
    const float* x   = (const float*)d_in[0];
    const float* ew  = (const float*)d_in[1];
    const float* W1  = (const float*)d_in[2];
    const float* b1  = (const float*)d_in[3];
    const float* W2  = (const float*)d_in[4];
    const float* b2  = (const float*)d_in[5];
    const float* W3  = (const float*)d_in[6];
    const float* b3  = (const float*)d_in[7];
    const int*   eidx  = (const int*)d_in[8];
    const int*   batch = (const int*)d_in[9];
    float* out = (float*)d_out;

    const int E = in_sizes[1];       // 1,600,000
    const int N = in_sizes[9];       // 100,000 (< 131072: fits 17-bit src pack)
    const int G = 64;
    const int* src = eidx;
    const int* dst = eidx + E;

    // workspace: A/B (fp16 features) double as CSR-build scratch
    // (bedge in A: E*8B == N*64*2B exactly; hcnt/btot in B), both dead by the
    // time features first touch them. C holds the final fp32 layer for pooling.
    char* p = (char*)d_ws;
    __half* A     = (__half*)p;                p += (size_t)N * 64 * sizeof(__half);
    __half* B     = (__half*)p;                p += (size_t)N * 64 * sizeof(__half);
    float* C      = (float*)p;                 p += (size_t)N * 64 * sizeof(float);
    float* dis    = (float*)p;                 p += (size_t)N * sizeof(float);
    int*   rowptr = (int*)p;                   p += (size_t)(N + 1) * sizeof(int);
    int*   bbase  = (int*)p;                   p += (size_t)(NB + 1) * sizeof(int);
    float* acc    = (float*)p;                 p += (size_t)G * 64 * sizeof(float);
    p = (char*)(((uintptr_t)p + 7) & ~(uintptr_t)7);
    int2*  em     = (int2*)p;                  // E entries, 8B

    int2* bedge = (int2*)A;                    // E*8B == N*64*2B
    int*  hcnt  = (int*)B;                     // NB*PBLK*4B = 1MB
    int*  btot  = (int*)B + NB * PBLK;         // NB ints

    const int BT = 256;
    const int FUSED_BLOCKS = 3125;             // 12500 waves x 8 rows = 100k

    // --- CSR build: LDS counting sort, zero global atomics ---
    k_bhist<<<PBLK, 256, 0, stream>>>(dst, hcnt, E);
    k_bscan<<<NB, 256, 0, stream>>>(hcnt, btot);
    k_bbase<<<1, 256, 0, stream>>>(btot, bbase, rowptr, N, E);
    k_bpart<<<PBLK, 256, 0, stream>>>(src, dst, ew, hcnt, bbase, bedge, E);
    k_bucket<<<NB, 256, 0, stream>>>(bedge, bbase, dis, rowptr, em, N);

    // --- layer 1: hs1 = fp16(dis*x) -> B ; fused agg+mm+silu*dis -> A ---
    // (B's hcnt scratch is dead after k_bpart; A's bedge dead after k_bucket)
    k_scale<<<(N * 32 + BT - 1) / BT, BT, 0, stream>>>(x, dis, (__half*)B, N * 32);
    k_aggmm32<<<FUSED_BLOCKS, BT, 0, stream>>>((__half*)B, em, rowptr, dis, W1, b1, A, N);

    // --- layer 2: fused agg+mm+silu*dis -> B ---
    k_aggmm64<true, __half><<<FUSED_BLOCKS, BT, 0, stream>>>(A, em, rowptr, dis, W2, b2, B, N);

    // --- layer 3: fused agg+mm+silu (raw fp32, for pooling) -> C ---
    k_aggmm64<false, float><<<FUSED_BLOCKS, BT, 0, stream>>>(B, em, rowptr, dis, W3, b3, C, N);

    // --- mean pool ---
    hipMemsetAsync(acc, 0, (size_t)G * 64 * sizeof(float), stream);
    k_pool_partial<<<(N + 127) / 128, BT, 0, stream>>>(C, batch, acc, N);
    k_pool_final<<<(G * 64) / BT, BT, 0, stream>>>(acc, batch, out, N);
}